// Round 9
// baseline (923.066 us; speedup 1.0000x reference)
//
#include <hip/hip_runtime.h>
#include <hip/hip_bf16.h>

#define N_NODES   20000
#define N_EDGES   100000
#define N_REL     1000
#define F_DIM     128
#define N_HEAD    4
#define HC        512      // N_HEAD * F_DIM
#define HC2       256      // HC/2 (bf16 pairs)
#define N_LAYERS  4
#define REL_EXT_ROWS 1008  // 1000 relations + 1 mean row
#define NEG_SLOPE 0.2f

typedef __attribute__((ext_vector_type(8))) short short8;
typedef __attribute__((ext_vector_type(4))) float floatx4;

__device__ __forceinline__ float loadIn(const void* p, size_t i, int f32) {
    if (f32) return ((const float*)p)[i];
    union { unsigned int u; float f; } c;
    c.u = ((unsigned int)((const unsigned short*)p)[i]) << 16;
    return c.f;
}

__device__ __forceinline__ unsigned short f2bf(float v) {
    __hip_bfloat16 b = __float2bfloat16(v);
    return *(unsigned short*)&b;
}

__device__ __forceinline__ void unpack2(unsigned int u, float& lo, float& hi) {
    union { unsigned int u; float f; } a, b;
    a.u = u << 16;
    b.u = u & 0xFFFF0000u;
    lo = a.f; hi = b.f;
}

// ---------------- dtype detection ----------------
__global__ void detect_kernel(const unsigned short* __restrict__ x, int* __restrict__ flag) {
    int t = threadIdx.x;  // 64
    int cnt = 0;
    for (int j = t; j < 256; j += 64) {
        int e = (x[j] >> 7) & 0xFF;
        if (e >= 143) cnt++;
    }
    for (int off = 32; off; off >>= 1) cnt += __shfl_xor(cnt, off);
    if (t == 0) flag[0] = (cnt >= 8) ? 1 : 0;
}

// ---------------- preprocessing ----------------

__global__ void hist_kernel(const int* __restrict__ dst, const int* __restrict__ rel,
                            int* __restrict__ deg, int* __restrict__ rcount) {
    int e = blockIdx.x * 256 + threadIdx.x;
    if (e < N_EDGES) {
        atomicAdd(&deg[dst[e]], 1);
        atomicAdd(&rcount[rel[e]], 1);
    }
}

__global__ void ea_mean_kernel(const int* __restrict__ rcount,
                               const void* __restrict__ relations,
                               float* __restrict__ ea_mean, const int* __restrict__ flag) {
    int f32 = flag[0];
    int b = blockIdx.x;
    int t = threadIdx.x;
    int col = t & 127;
    int rhalf = t >> 7;
    float acc = 0.f;
    for (int j = 0; j < 4; ++j) {
        int r = b * 8 + j * 2 + rhalf;
        acc += (float)rcount[r] * loadIn(relations, (size_t)r * F_DIM + col, f32);
    }
    __shared__ float part[256];
    part[t] = acc;
    __syncthreads();
    if (t < 128)
        atomicAdd(&ea_mean[col], (part[t] + part[t + 128]) * (1.f / (float)N_EDGES));
}

__global__ void relext_kernel(const void* __restrict__ relations,
                              const float* __restrict__ ea_mean,
                              unsigned short* __restrict__ rel_ext, const int* __restrict__ flag) {
    int idx = blockIdx.x * 256 + threadIdx.x;
    if (idx >= REL_EXT_ROWS * F_DIM) return;
    int f32 = flag[0];
    int r = idx >> 7;
    int c = idx & 127;
    float v;
    if (r < N_REL)       v = loadIn(relations, idx, f32);
    else if (r == N_REL) v = ea_mean[c];
    else                 v = 0.f;
    rel_ext[idx] = f2bf(v);
}

__global__ void scan_kernel(const int* __restrict__ deg,
                            int* __restrict__ row_start, int* __restrict__ cursor) {
    __shared__ int part[1024];
    int t = threadIdx.x;
    const int CH = (N_NODES + 1023) / 1024;  // 20
    int base = t * CH;
    int sum = 0;
    for (int j = 0; j < CH; ++j) {
        int idx = base + j;
        if (idx < N_NODES) sum += deg[idx];
    }
    part[t] = sum;
    __syncthreads();
    for (int off = 1; off < 1024; off <<= 1) {
        int u = (t >= off) ? part[t - off] : 0;
        __syncthreads();
        part[t] += u;
        __syncthreads();
    }
    int run = part[t] - sum;
    for (int j = 0; j < CH; ++j) {
        int idx = base + j;
        if (idx < N_NODES) {
            row_start[idx] = run;
            cursor[idx] = run;
            run += deg[idx];
        }
    }
    if (t == 1023) row_start[N_NODES] = part[1023];
}

__global__ void scatter_kernel(const int* __restrict__ src, const int* __restrict__ dst,
                               const int* __restrict__ rel, int* __restrict__ cursor,
                               int* __restrict__ csr_pack, int* __restrict__ csr_dst) {
    int e = blockIdx.x * 256 + threadIdx.x;
    if (e < N_EDGES) {
        int d = dst[e];
        int p = atomicAdd(&cursor[d], 1);
        csr_pack[p] = src[e] | (rel[e] << 16);
        csr_dst[p] = d;
    }
}

__global__ void tail_kernel(const void* __restrict__ relations, void* __restrict__ out,
                            const int* __restrict__ flag) {
    int i = blockIdx.x * 256 + threadIdx.x;
    if (i >= N_REL * F_DIM) return;
    int f32 = flag[0];
    float v = loadIn(relations, i, f32);
    size_t o = (size_t)N_NODES * F_DIM + i;
    if (f32) ((float*)out)[o] = v;
    else     ((unsigned short*)out)[o] = f2bf(v);
}

// ---------------- weight transpose: W[l][128 k][512 n] -> Wt[mat][512 n][128 k] bf16 ----------------
__global__ void w_transpose_kernel(const void* __restrict__ Wl, const void* __restrict__ Wr,
                                   const void* __restrict__ We,
                                   unsigned short* __restrict__ Wt, const int* __restrict__ flag) {
    int f32 = flag[0];
    int k0 = blockIdx.x * 64;
    int n0 = blockIdx.y * 64;
    int mat = blockIdx.z;
    const void* src = (mat < 4) ? Wl : (mat < 8 ? Wr : We);
    size_t base = (size_t)(mat & 3) * F_DIM * HC;
    unsigned short* dst = Wt + (size_t)mat * HC * F_DIM;
    __shared__ float T[64][65];
    int t = threadIdx.x;
    int r = t >> 2, cq = t & 3;
    for (int j = 0; j < 16; ++j) {
        int n = cq * 16 + j;
        T[n][r] = loadIn(src, base + (size_t)(k0 + r) * HC + n0 + n, f32);
    }
    __syncthreads();
    for (int j = 0; j < 16; ++j) {
        int k = cq * 16 + j;
        dst[(size_t)(n0 + r) * F_DIM + k0 + k] = f2bf(T[r][k]);
    }
}

// ---------------- projection GEMM (latency-optimized grid) ----------------
__launch_bounds__(256, 4)
__global__ void proj_kernel(const void* __restrict__ A, int a_input, int M,
                            const unsigned short* __restrict__ Wt0,
                            const unsigned short* __restrict__ Wt1,
                            const void* __restrict__ bias0, size_t b0_off,
                            const void* __restrict__ bias1, size_t b1_off,
                            unsigned short* __restrict__ out0,
                            unsigned short* __restrict__ out1,
                            int tpb, const int* __restrict__ flag) {
    __shared__ __align__(16) short As[64][136];    // 17.4 KB
    __shared__ __align__(16) short BtRaw[128 * 72];// 18.4 KB; Cs view: stride 136, 64 rows
    int f32 = flag[0];
    int a_f32 = a_input ? f32 : 0;
    int m0 = blockIdx.x * 64;
    int t = threadIdx.x;

    for (int j = 0; j < 4; ++j) {
        int c = t + j * 256;
        int row = c >> 4;
        int colc = (c & 15) * 8;
        int gm = m0 + row;
        short8 v = (short8){0, 0, 0, 0, 0, 0, 0, 0};
        if (gm < M) {
            size_t idx = (size_t)gm * F_DIM + colc;
            if (a_f32) {
                const float* Af = (const float*)A;
                for (int q = 0; q < 8; ++q) v[q] = (short)f2bf(Af[idx + q]);
            } else {
                v = *(const short8*)((const unsigned short*)A + idx);
            }
        }
        *(short8*)&As[row][colc] = v;
    }

    int wave = t >> 6, lane = t & 63;
    int wm = (wave >> 1) * 32, wn = (wave & 1) * 64;
    int r16 = lane & 15, quad = lane >> 4;

    for (int it = 0; it < tpb; ++it) {
        int nt = blockIdx.y * tpb + it;
        const unsigned short* Wt = (nt < 4) ? Wt0 : Wt1;
        int n0 = (nt & 3) * 128;

        floatx4 acc[2][4];
        for (int mi = 0; mi < 2; ++mi)
            for (int ni = 0; ni < 4; ++ni)
                acc[mi][ni] = (floatx4){0.f, 0.f, 0.f, 0.f};

        for (int half = 0; half < 2; ++half) {
            __syncthreads();
            for (int j = 0; j < 4; ++j) {
                int c = t + j * 256;
                int nl = c >> 3;
                int kc = (c & 7) * 8;
                *(short8*)&BtRaw[nl * 72 + kc] =
                    *(const short8*)(Wt + (size_t)(n0 + nl) * F_DIM + half * 64 + kc);
            }
            __syncthreads();

            for (int kk = 0; kk < 2; ++kk) {
                short8 a[2], b[4];
                for (int mi = 0; mi < 2; ++mi)
                    a[mi] = *(const short8*)&As[wm + mi * 16 + r16][half * 64 + kk * 32 + quad * 8];
                for (int ni = 0; ni < 4; ++ni)
                    b[ni] = *(const short8*)&BtRaw[(wn + ni * 16 + r16) * 72 + kk * 32 + quad * 8];
                for (int mi = 0; mi < 2; ++mi)
                    for (int ni = 0; ni < 4; ++ni)
                        acc[mi][ni] = __builtin_amdgcn_mfma_f32_16x16x32_bf16(a[mi], b[ni], acc[mi][ni], 0, 0, 0);
            }
        }

        const void* bias = (nt < 4) ? bias0 : bias1;
        size_t boff = (nt < 4) ? b0_off : b1_off;
        unsigned short* out = (nt < 4) ? out0 : out1;
        __syncthreads();
        for (int mi = 0; mi < 2; ++mi) {
            for (int ni = 0; ni < 4; ++ni) {
                int col = wn + ni * 16 + r16;
                float bv = bias ? loadIn(bias, boff + n0 + col, f32) : 0.f;
                for (int r = 0; r < 4; ++r) {
                    int rowl = wm + mi * 16 + quad * 4 + r;
                    BtRaw[rowl * 136 + col] = (short)f2bf(acc[mi][ni][r] + bv);
                }
            }
        }
        __syncthreads();
        for (int j = 0; j < 4; ++j) {
            int c = t + j * 256;
            int rowl = c >> 4;
            int colc = (c & 15) * 8;
            int gm = m0 + rowl;
            if (gm < M)
                *(short8*)(out + (size_t)gm * HC + n0 + colc) =
                    *(const short8*)&BtRaw[rowl * 136 + colc];
        }
    }
}

// ---------------- score kernel: one wave per (edge or self-loop) ----------------
// Virtual edge v: v < N_EDGES -> CSR slot v (src/rel from csr_pack, dst from csr_dst);
// else self-loop of node v-N_EDGES (src=dst=node, rel=mean row).
// Lane covers channels [lane*8, lane*8+8); per-head 16-lane reduce; writes logits[v][4].
__launch_bounds__(256)
__global__ void score_kernel(const uint4* __restrict__ xl4, const uint4* __restrict__ xr4,
                             const uint4* __restrict__ re4,
                             const int* __restrict__ csr_pack, const int* __restrict__ csr_dst,
                             const void* __restrict__ att, size_t att_off,
                             float* __restrict__ logits, const int* __restrict__ flag) {
    int f32 = flag[0];
    int w = threadIdx.x >> 6, lane = threadIdx.x & 63;
    int v = blockIdx.x * 4 + w;
    if (v >= N_EDGES + N_NODES) return;
    int src, dst, rr;
    if (v < N_EDGES) {
        int pk = csr_pack[v];
        src = pk & 0xFFFF;        if (src >= N_NODES) src = 0;
        rr  = (pk >> 16) & 0x3FF; if (rr > N_REL) rr = N_REL;
        dst = csr_dst[v];         if (dst < 0 || dst >= N_NODES) dst = 0;
    } else {
        src = dst = v - N_EDGES;
        rr = N_REL;
    }
    uint4 xu = xl4[(size_t)src * 64 + lane];
    uint4 yu = xr4[(size_t)dst * 64 + lane];
    uint4 ru = re4[(size_t)rr * 64 + lane];
    float xv[8], yv[8], rv[8];
    unpack2(xu.x, xv[0], xv[1]); unpack2(xu.y, xv[2], xv[3]);
    unpack2(xu.z, xv[4], xv[5]); unpack2(xu.w, xv[6], xv[7]);
    unpack2(yu.x, yv[0], yv[1]); unpack2(yu.y, yv[2], yv[3]);
    unpack2(yu.z, yv[4], yv[5]); unpack2(yu.w, yv[6], yv[7]);
    unpack2(ru.x, rv[0], rv[1]); unpack2(ru.y, rv[2], rv[3]);
    unpack2(ru.z, rv[4], rv[5]); unpack2(ru.w, rv[6], rv[7]);
    float part = 0.f;
    for (int q = 0; q < 8; ++q) {
        float u = xv[q] + yv[q] + rv[q];
        u = (u > 0.f) ? u : NEG_SLOPE * u;
        part += u * loadIn(att, att_off + lane * 8 + q, f32);
    }
    for (int off = 8; off; off >>= 1) part += __shfl_xor(part, off);
    if ((lane & 15) == 0) logits[(size_t)v * 4 + (lane >> 4)] = part;
}

// ---------------- agg kernel: per-node softmax over precomputed logits + gather ----------------
// One block per node; wave w = head w; lane owns channels (2*lane, 2*lane+1) of its head.
// ONE max/sum reduce pair per node (not per edge); gather loop is dependence-free FMA
// with next-slot value prefetch.
__launch_bounds__(256)
__global__ void agg_kernel(const unsigned int* __restrict__ xl2,
                           const int* __restrict__ row_start,
                           const int* __restrict__ csr_pack,
                           const float* __restrict__ logits,
                           const void* __restrict__ bias, size_t bias_off,
                           void* __restrict__ hout, int final_layer,
                           const int* __restrict__ flag) {
    __shared__ float lsum[N_HEAD][F_DIM];
    int f32 = flag[0];
    int i = blockIdx.x;
    int t = threadIdx.x, w = t >> 6, lane = t & 63;
    int pidx = w * 64 + lane;

    int e0 = row_start[i], e1 = row_start[i + 1];
    if (e0 < 0) e0 = 0;
    if (e1 > N_EDGES) e1 = N_EDGES;
    if (e1 < e0) e1 = e0;
    int cnt = (e1 - e0) + 1;   // slot 0 = self-loop

    // pass 1: head max over slots
    float mx = -3.0e38f;
    for (int sl = lane; sl < cnt; sl += 64) {
        float lg = (sl == 0) ? logits[((size_t)N_EDGES + i) * 4 + w]
                             : logits[(size_t)(e0 + sl - 1) * 4 + w];
        mx = fmaxf(mx, lg);
    }
    for (int off = 32; off; off >>= 1) mx = fmaxf(mx, __shfl_xor(mx, off));
    // pass 2: sum of exp
    float sm = 0.f;
    for (int sl = lane; sl < cnt; sl += 64) {
        float lg = (sl == 0) ? logits[((size_t)N_EDGES + i) * 4 + w]
                             : logits[(size_t)(e0 + sl - 1) * 4 + w];
        sm += __expf(lg - mx);
    }
    for (int off = 32; off; off >>= 1) sm += __shfl_xor(sm, off);

    // pass 3: weighted gather (prefetched, independent FMAs)
    float acc0 = 0.f, acc1 = 0.f;
    float lgc = logits[((size_t)N_EDGES + i) * 4 + w];
    unsigned int uc = xl2[(size_t)i * HC2 + pidx];
    for (int slot = 0; slot < cnt; ++slot) {
        float lgn = 0.f; unsigned int un = 0;
        if (slot + 1 < cnt) {
            int pk = csr_pack[e0 + slot];
            int sn = pk & 0xFFFF; if (sn >= N_NODES) sn = 0;
            lgn = logits[(size_t)(e0 + slot) * 4 + w];
            un = xl2[(size_t)sn * HC2 + pidx];
        }
        float p = __expf(lgc - mx);
        float v0, v1; unpack2(uc, v0, v1);
        acc0 += p * v0;
        acc1 += p * v1;
        lgc = lgn; uc = un;
    }
    float inv = 1.f / sm;
    lsum[w][2 * lane]     = acc0 * inv;
    lsum[w][2 * lane + 1] = acc1 * inv;
    __syncthreads();
    if (t < F_DIM) {
        int c = t;
        float v = (lsum[0][c] + lsum[1][c] + lsum[2][c] + lsum[3][c]) * 0.25f
                + loadIn(bias, bias_off + c, f32);
        size_t o = (size_t)i * F_DIM + c;
        if (final_layer && f32) ((float*)hout)[o] = v;
        else                    ((unsigned short*)hout)[o] = f2bf(v);
    }
}

// ---------------- launch ----------------

extern "C" void kernel_launch(void* const* d_in, const int* in_sizes, int n_in,
                              void* d_out, int out_size, void* d_ws, size_t ws_size,
                              hipStream_t stream) {
    const void* x          = d_in[0];
    const int*  edge_index = (const int*)d_in[1];
    const void* relations  = d_in[2];
    const int*  rel_index  = (const int*)d_in[3];
    const void* Wl         = d_in[4];
    const void* bl         = d_in[5];
    const void* Wr         = d_in[6];
    const void* br         = d_in[7];
    const void* We         = d_in[8];
    const void* att        = d_in[9];
    const void* bias       = d_in[10];

    char* ws = (char*)d_ws;
    size_t off = 0;
    auto alloc = [&](size_t bytes) -> void* {
        void* p = ws + off;
        off = (off + bytes + 255) & ~(size_t)255;
        return p;
    };
    int*            flag     = (int*)alloc(4);
    int*            deg      = (int*)alloc(N_NODES * 4);
    int*            row_start= (int*)alloc((N_NODES + 1) * 4);
    int*            cursor   = (int*)alloc(N_NODES * 4);
    int*            rcount   = (int*)alloc(N_REL * 4);
    float*          ea_mean  = (float*)alloc(F_DIM * 4);
    int*            csr_pack = (int*)alloc(N_EDGES * 4);
    int*            csr_dst  = (int*)alloc(N_EDGES * 4);
    float*          logits   = (float*)alloc((size_t)(N_EDGES + N_NODES) * 4 * 4);  // 1.92 MB
    unsigned short* rel_ext  = (unsigned short*)alloc((size_t)REL_EXT_ROWS * F_DIM * 2);
    unsigned short* Wt       = (unsigned short*)alloc((size_t)12 * HC * F_DIM * 2);  // 1.57 MB
    unsigned short* re       = (unsigned short*)alloc((size_t)REL_EXT_ROWS * HC * 2);
    unsigned short* hbuf     = (unsigned short*)alloc((size_t)N_NODES * F_DIM * 2);
    unsigned short* xl       = (unsigned short*)alloc((size_t)N_NODES * HC * 2);
    unsigned short* xr       = (unsigned short*)alloc((size_t)N_NODES * HC * 2);
    // total ~52 MB

    const int* esrc = edge_index;
    const int* edst = edge_index + N_EDGES;

    detect_kernel<<<1, 64, 0, stream>>>((const unsigned short*)x, flag);
    hipMemsetAsync(rcount, 0, N_REL * 4, stream);
    hipMemsetAsync(deg, 0, N_NODES * 4, stream);
    hipMemsetAsync(ea_mean, 0, F_DIM * 4, stream);
    hist_kernel<<<(N_EDGES + 255) / 256, 256, 0, stream>>>(edst, rel_index, deg, rcount);
    ea_mean_kernel<<<N_REL / 8, 256, 0, stream>>>(rcount, relations, ea_mean, flag);
    relext_kernel<<<(REL_EXT_ROWS * F_DIM + 255) / 256, 256, 0, stream>>>(relations, ea_mean, rel_ext, flag);
    scan_kernel<<<1, 1024, 0, stream>>>(deg, row_start, cursor);
    scatter_kernel<<<(N_EDGES + 255) / 256, 256, 0, stream>>>(esrc, edst, rel_index, cursor,
                                                              csr_pack, csr_dst);
    w_transpose_kernel<<<dim3(2, 8, 12), 256, 0, stream>>>(Wl, Wr, We, Wt, flag);
    tail_kernel<<<(N_REL * F_DIM + 255) / 256, 256, 0, stream>>>(relations, d_out, flag);

    const int score_blocks = (N_EDGES + N_NODES + 3) / 4;   // 30000
    const void* hin = x;
    int a_input = 1;
    for (int l = 0; l < N_LAYERS; ++l) {
        const unsigned short* Wlt = Wt + (size_t)l * HC * F_DIM;
        const unsigned short* Wrt = Wt + (size_t)(4 + l) * HC * F_DIM;
        const unsigned short* Wet = Wt + (size_t)(8 + l) * HC * F_DIM;
        proj_kernel<<<dim3((N_NODES + 63) / 64, 4), 256, 0, stream>>>(
            hin, a_input, N_NODES, Wlt, Wrt,
            bl, (size_t)l * HC, br, (size_t)l * HC,
            xl, xr, 2, flag);
        proj_kernel<<<dim3((REL_EXT_ROWS + 63) / 64, 4), 256, 0, stream>>>(
            rel_ext, 0, REL_EXT_ROWS, Wet, nullptr,
            nullptr, 0, nullptr, 0,
            re, nullptr, 1, flag);
        score_kernel<<<score_blocks, 256, 0, stream>>>(
            (const uint4*)xl, (const uint4*)xr, (const uint4*)re,
            csr_pack, csr_dst, att, (size_t)l * N_HEAD * F_DIM, logits, flag);
        int final_layer = (l == N_LAYERS - 1);
        void* hout = final_layer ? d_out : (void*)hbuf;
        agg_kernel<<<N_NODES, 256, 0, stream>>>(
            (const unsigned int*)xl, row_start, csr_pack, logits,
            bias, (size_t)l * F_DIM, hout, final_layer, flag);
        hin = hbuf;
        a_input = 0;
    }
}

// Round 10
// 621.462 us; speedup vs baseline: 1.4853x; 1.4853x over previous
//
#include <hip/hip_runtime.h>
#include <hip/hip_bf16.h>

#define N_NODES   20000
#define N_EDGES   100000
#define N_REL     1000
#define F_DIM     128
#define N_HEAD    4
#define HC        512      // N_HEAD * F_DIM
#define HC2       256      // HC/2 (bf16 pairs)
#define N_LAYERS  4
#define REL_EXT_ROWS 1008  // 1000 relations + 1 mean row
#define NEG_SLOPE 0.2f

typedef __attribute__((ext_vector_type(8))) short short8;
typedef __attribute__((ext_vector_type(4))) float floatx4;

__device__ __forceinline__ float loadIn(const void* p, size_t i, int f32) {
    if (f32) return ((const float*)p)[i];
    union { unsigned int u; float f; } c;
    c.u = ((unsigned int)((const unsigned short*)p)[i]) << 16;
    return c.f;
}

__device__ __forceinline__ unsigned short f2bf(float v) {
    __hip_bfloat16 b = __float2bfloat16(v);
    return *(unsigned short*)&b;
}

__device__ __forceinline__ void unpack2(unsigned int u, float& lo, float& hi) {
    union { unsigned int u; float f; } a, b;
    a.u = u << 16;
    b.u = u & 0xFFFF0000u;
    lo = a.f; hi = b.f;
}

// ---------------- dtype detection ----------------
__global__ void detect_kernel(const unsigned short* __restrict__ x, int* __restrict__ flag) {
    int t = threadIdx.x;  // 64
    int cnt = 0;
    for (int j = t; j < 256; j += 64) {
        int e = (x[j] >> 7) & 0xFF;
        if (e >= 143) cnt++;
    }
    for (int off = 32; off; off >>= 1) cnt += __shfl_xor(cnt, off);
    if (t == 0) flag[0] = (cnt >= 8) ? 1 : 0;
}

// ---------------- preprocessing ----------------

__global__ void hist_kernel(const int* __restrict__ dst, const int* __restrict__ rel,
                            int* __restrict__ deg, int* __restrict__ rcount) {
    int e = blockIdx.x * 256 + threadIdx.x;
    if (e < N_EDGES) {
        atomicAdd(&deg[dst[e]], 1);
        atomicAdd(&rcount[rel[e]], 1);
    }
}

__global__ void ea_mean_kernel(const int* __restrict__ rcount,
                               const void* __restrict__ relations,
                               float* __restrict__ ea_mean, const int* __restrict__ flag) {
    int f32 = flag[0];
    int b = blockIdx.x;
    int t = threadIdx.x;
    int col = t & 127;
    int rhalf = t >> 7;
    float acc = 0.f;
    for (int j = 0; j < 4; ++j) {
        int r = b * 8 + j * 2 + rhalf;
        acc += (float)rcount[r] * loadIn(relations, (size_t)r * F_DIM + col, f32);
    }
    __shared__ float part[256];
    part[t] = acc;
    __syncthreads();
    if (t < 128)
        atomicAdd(&ea_mean[col], (part[t] + part[t + 128]) * (1.f / (float)N_EDGES));
}

__global__ void relext_kernel(const void* __restrict__ relations,
                              const float* __restrict__ ea_mean,
                              unsigned short* __restrict__ rel_ext, const int* __restrict__ flag) {
    int idx = blockIdx.x * 256 + threadIdx.x;
    if (idx >= REL_EXT_ROWS * F_DIM) return;
    int f32 = flag[0];
    int r = idx >> 7;
    int c = idx & 127;
    float v;
    if (r < N_REL)       v = loadIn(relations, idx, f32);
    else if (r == N_REL) v = ea_mean[c];
    else                 v = 0.f;
    rel_ext[idx] = f2bf(v);
}

__global__ void scan_kernel(const int* __restrict__ deg,
                            int* __restrict__ row_start, int* __restrict__ cursor) {
    __shared__ int part[1024];
    int t = threadIdx.x;
    const int CH = (N_NODES + 1023) / 1024;  // 20
    int base = t * CH;
    int sum = 0;
    for (int j = 0; j < CH; ++j) {
        int idx = base + j;
        if (idx < N_NODES) sum += deg[idx];
    }
    part[t] = sum;
    __syncthreads();
    for (int off = 1; off < 1024; off <<= 1) {
        int u = (t >= off) ? part[t - off] : 0;
        __syncthreads();
        part[t] += u;
        __syncthreads();
    }
    int run = part[t] - sum;
    for (int j = 0; j < CH; ++j) {
        int idx = base + j;
        if (idx < N_NODES) {
            row_start[idx] = run;
            cursor[idx] = run;
            run += deg[idx];
        }
    }
    if (t == 1023) row_start[N_NODES] = part[1023];
}

__global__ void scatter_kernel(const int* __restrict__ src, const int* __restrict__ dst,
                               const int* __restrict__ rel, int* __restrict__ cursor,
                               int* __restrict__ csr_pack) {
    int e = blockIdx.x * 256 + threadIdx.x;
    if (e < N_EDGES) {
        int d = dst[e];
        int p = atomicAdd(&cursor[d], 1);
        csr_pack[p] = src[e] | (rel[e] << 16);
    }
}

__global__ void tail_kernel(const void* __restrict__ relations, void* __restrict__ out,
                            const int* __restrict__ flag) {
    int i = blockIdx.x * 256 + threadIdx.x;
    if (i >= N_REL * F_DIM) return;
    int f32 = flag[0];
    float v = loadIn(relations, i, f32);
    size_t o = (size_t)N_NODES * F_DIM + i;
    if (f32) ((float*)out)[o] = v;
    else     ((unsigned short*)out)[o] = f2bf(v);
}

// ---------------- weight transpose: W[l][128 k][512 n] -> Wt[mat][512 n][128 k] bf16 ----------------
__global__ void w_transpose_kernel(const void* __restrict__ Wl, const void* __restrict__ Wr,
                                   const void* __restrict__ We,
                                   unsigned short* __restrict__ Wt, const int* __restrict__ flag) {
    int f32 = flag[0];
    int k0 = blockIdx.x * 64;
    int n0 = blockIdx.y * 64;
    int mat = blockIdx.z;
    const void* src = (mat < 4) ? Wl : (mat < 8 ? Wr : We);
    size_t base = (size_t)(mat & 3) * F_DIM * HC;
    unsigned short* dst = Wt + (size_t)mat * HC * F_DIM;
    __shared__ float T[64][65];
    int t = threadIdx.x;
    int r = t >> 2, cq = t & 3;
    for (int j = 0; j < 16; ++j) {
        int n = cq * 16 + j;
        T[n][r] = loadIn(src, base + (size_t)(k0 + r) * HC + n0 + n, f32);
    }
    __syncthreads();
    for (int j = 0; j < 16; ++j) {
        int k = cq * 16 + j;
        dst[(size_t)(n0 + r) * F_DIM + k0 + k] = f2bf(T[r][k]);
    }
}

// ---------------- projection GEMM (latency-optimized grid) ----------------
__launch_bounds__(256, 4)
__global__ void proj_kernel(const void* __restrict__ A, int a_input, int M,
                            const unsigned short* __restrict__ Wt0,
                            const unsigned short* __restrict__ Wt1,
                            const void* __restrict__ bias0, size_t b0_off,
                            const void* __restrict__ bias1, size_t b1_off,
                            unsigned short* __restrict__ out0,
                            unsigned short* __restrict__ out1,
                            int tpb, const int* __restrict__ flag) {
    __shared__ __align__(16) short As[64][136];    // 17.4 KB
    __shared__ __align__(16) short BtRaw[128 * 72];// 18.4 KB; Cs view: stride 136, 64 rows
    int f32 = flag[0];
    int a_f32 = a_input ? f32 : 0;
    int m0 = blockIdx.x * 64;
    int t = threadIdx.x;

    for (int j = 0; j < 4; ++j) {
        int c = t + j * 256;
        int row = c >> 4;
        int colc = (c & 15) * 8;
        int gm = m0 + row;
        short8 v = (short8){0, 0, 0, 0, 0, 0, 0, 0};
        if (gm < M) {
            size_t idx = (size_t)gm * F_DIM + colc;
            if (a_f32) {
                const float* Af = (const float*)A;
                for (int q = 0; q < 8; ++q) v[q] = (short)f2bf(Af[idx + q]);
            } else {
                v = *(const short8*)((const unsigned short*)A + idx);
            }
        }
        *(short8*)&As[row][colc] = v;
    }

    int wave = t >> 6, lane = t & 63;
    int wm = (wave >> 1) * 32, wn = (wave & 1) * 64;
    int r16 = lane & 15, quad = lane >> 4;

    for (int it = 0; it < tpb; ++it) {
        int nt = blockIdx.y * tpb + it;
        const unsigned short* Wt = (nt < 4) ? Wt0 : Wt1;
        int n0 = (nt & 3) * 128;

        floatx4 acc[2][4];
        for (int mi = 0; mi < 2; ++mi)
            for (int ni = 0; ni < 4; ++ni)
                acc[mi][ni] = (floatx4){0.f, 0.f, 0.f, 0.f};

        for (int half = 0; half < 2; ++half) {
            __syncthreads();
            for (int j = 0; j < 4; ++j) {
                int c = t + j * 256;
                int nl = c >> 3;
                int kc = (c & 7) * 8;
                *(short8*)&BtRaw[nl * 72 + kc] =
                    *(const short8*)(Wt + (size_t)(n0 + nl) * F_DIM + half * 64 + kc);
            }
            __syncthreads();

            for (int kk = 0; kk < 2; ++kk) {
                short8 a[2], b[4];
                for (int mi = 0; mi < 2; ++mi)
                    a[mi] = *(const short8*)&As[wm + mi * 16 + r16][half * 64 + kk * 32 + quad * 8];
                for (int ni = 0; ni < 4; ++ni)
                    b[ni] = *(const short8*)&BtRaw[(wn + ni * 16 + r16) * 72 + kk * 32 + quad * 8];
                for (int mi = 0; mi < 2; ++mi)
                    for (int ni = 0; ni < 4; ++ni)
                        acc[mi][ni] = __builtin_amdgcn_mfma_f32_16x16x32_bf16(a[mi], b[ni], acc[mi][ni], 0, 0, 0);
            }
        }

        const void* bias = (nt < 4) ? bias0 : bias1;
        size_t boff = (nt < 4) ? b0_off : b1_off;
        unsigned short* out = (nt < 4) ? out0 : out1;
        __syncthreads();
        for (int mi = 0; mi < 2; ++mi) {
            for (int ni = 0; ni < 4; ++ni) {
                int col = wn + ni * 16 + r16;
                float bv = bias ? loadIn(bias, boff + n0 + col, f32) : 0.f;
                for (int r = 0; r < 4; ++r) {
                    int rowl = wm + mi * 16 + quad * 4 + r;
                    BtRaw[rowl * 136 + col] = (short)f2bf(acc[mi][ni][r] + bv);
                }
            }
        }
        __syncthreads();
        for (int j = 0; j < 4; ++j) {
            int c = t + j * 256;
            int rowl = c >> 4;
            int colc = (c & 15) * 8;
            int gm = m0 + rowl;
            if (gm < M)
                *(short8*)(out + (size_t)gm * HC + n0 + colc) =
                    *(const short8*)&BtRaw[rowl * 136 + colc];
        }
    }
}

// ---------------- edge kernel: full-row waves, edge-parallel, no-max softmax ----------------
// One block per dst node. Each wave owns the FULL 512-ch row (lane = channels
// [lane*8, lane*8+8), head = lane>>4) and processes slots slot%4==w independently:
// slot 0 = self-loop (mean rel row), slot k>0 = CSR edge e0+k-1.
// Per edge: ONE xl-row + ONE re-row gather (2 KB), 4-step 16-lane reduce, p=exp(clamped
// logit) (no max subtraction — logits are O(10), guarded by +-60 clamp; ratio identical),
// s += p, acc += p*xv. No in-loop barriers/LDS. Final: merge 4 wave partials via LDS.
__launch_bounds__(256)
__global__ void edge_kernel(const uint4* __restrict__ xl4,
                            const uint4* __restrict__ xr4,
                            const uint4* __restrict__ re4,
                            const int* __restrict__ row_start,
                            const int* __restrict__ csr_pack,
                            const void* __restrict__ att, size_t att_off,
                            const void* __restrict__ bias, size_t bias_off,
                            void* __restrict__ hout, int final_layer,
                            const int* __restrict__ flag) {
    __shared__ float lacc[N_HEAD][HC];      // [wave][512] partials, 8 KB
    __shared__ float sW[N_HEAD][N_HEAD];    // [wave][head] partial sums

    int f32 = flag[0];
    int i = blockIdx.x;
    int t = threadIdx.x, w = t >> 6, lane = t & 63;

    // per-lane row data: channels [lane*8, lane*8+8)
    float xrv[8], attv[8];
    {
        uint4 u = xr4[(size_t)i * 64 + lane];
        unpack2(u.x, xrv[0], xrv[1]); unpack2(u.y, xrv[2], xrv[3]);
        unpack2(u.z, xrv[4], xrv[5]); unpack2(u.w, xrv[6], xrv[7]);
        for (int q = 0; q < 8; ++q)
            attv[q] = loadIn(att, att_off + lane * 8 + q, f32);
    }

    int e0 = row_start[i], e1 = row_start[i + 1];
    if (e0 < 0) e0 = 0;
    if (e1 > N_EDGES) e1 = N_EDGES;
    if (e1 < e0) e1 = e0;
    int total = (e1 - e0) + 1;   // + self-loop at slot 0

    float s = 0.f;
    float acc[8];
    for (int q = 0; q < 8; ++q) acc[q] = 0.f;

    for (int slot = w; slot < total; slot += 4) {
        int src, rr;
        if (slot == 0) { src = i; rr = N_REL; }
        else {
            int pk = csr_pack[e0 + slot - 1];
            src = pk & 0xFFFF;        if (src >= N_NODES) src = 0;
            rr  = (pk >> 16) & 0x3FF; if (rr > N_REL) rr = N_REL;
        }
        uint4 xu = xl4[(size_t)src * 64 + lane];
        uint4 ru = re4[(size_t)rr * 64 + lane];
        float xv[8], rv[8];
        unpack2(xu.x, xv[0], xv[1]); unpack2(xu.y, xv[2], xv[3]);
        unpack2(xu.z, xv[4], xv[5]); unpack2(xu.w, xv[6], xv[7]);
        unpack2(ru.x, rv[0], rv[1]); unpack2(ru.y, rv[2], rv[3]);
        unpack2(ru.z, rv[4], rv[5]); unpack2(ru.w, rv[6], rv[7]);
        float part = 0.f;
        for (int q = 0; q < 8; ++q) {
            float u = xv[q] + xrv[q] + rv[q];
            u = fmaxf(u, NEG_SLOPE * u);   // leaky_relu
            part += u * attv[q];
        }
        // 16-lane (head-group) reduce
        for (int off = 8; off; off >>= 1) part += __shfl_xor(part, off);
        part = fminf(fmaxf(part, -60.f), 60.f);
        float p = __expf(part);
        s += p;
        for (int q = 0; q < 8; ++q) acc[q] += p * xv[q];
    }

    // merge 4 wave partials
    for (int q = 0; q < 8; ++q) lacc[w][lane * 8 + q] = acc[q];
    if ((lane & 15) == 0) sW[w][lane >> 4] = s;
    __syncthreads();
    if (t < F_DIM) {
        int c = t;
        float v = 0.f;
        for (int h = 0; h < N_HEAD; ++h) {
            float S = sW[0][h] + sW[1][h] + sW[2][h] + sW[3][h];
            float a = lacc[0][h * F_DIM + c] + lacc[1][h * F_DIM + c]
                    + lacc[2][h * F_DIM + c] + lacc[3][h * F_DIM + c];
            v += a / S;
        }
        v = v * 0.25f + loadIn(bias, bias_off + c, f32);
        size_t o = (size_t)i * F_DIM + c;
        if (final_layer && f32) ((float*)hout)[o] = v;
        else                    ((unsigned short*)hout)[o] = f2bf(v);
    }
}

// ---------------- launch ----------------

extern "C" void kernel_launch(void* const* d_in, const int* in_sizes, int n_in,
                              void* d_out, int out_size, void* d_ws, size_t ws_size,
                              hipStream_t stream) {
    const void* x          = d_in[0];
    const int*  edge_index = (const int*)d_in[1];
    const void* relations  = d_in[2];
    const int*  rel_index  = (const int*)d_in[3];
    const void* Wl         = d_in[4];
    const void* bl         = d_in[5];
    const void* Wr         = d_in[6];
    const void* br         = d_in[7];
    const void* We         = d_in[8];
    const void* att        = d_in[9];
    const void* bias       = d_in[10];

    char* ws = (char*)d_ws;
    size_t off = 0;
    auto alloc = [&](size_t bytes) -> void* {
        void* p = ws + off;
        off = (off + bytes + 255) & ~(size_t)255;
        return p;
    };
    int*            flag     = (int*)alloc(4);
    int*            deg      = (int*)alloc(N_NODES * 4);
    int*            row_start= (int*)alloc((N_NODES + 1) * 4);
    int*            cursor   = (int*)alloc(N_NODES * 4);
    int*            rcount   = (int*)alloc(N_REL * 4);
    float*          ea_mean  = (float*)alloc(F_DIM * 4);
    int*            csr_pack = (int*)alloc(N_EDGES * 4);
    unsigned short* rel_ext  = (unsigned short*)alloc((size_t)REL_EXT_ROWS * F_DIM * 2);
    unsigned short* Wt       = (unsigned short*)alloc((size_t)12 * HC * F_DIM * 2);  // 1.57 MB
    unsigned short* re       = (unsigned short*)alloc((size_t)REL_EXT_ROWS * HC * 2);
    unsigned short* hbuf     = (unsigned short*)alloc((size_t)N_NODES * F_DIM * 2);
    unsigned short* xl       = (unsigned short*)alloc((size_t)N_NODES * HC * 2);
    unsigned short* xr       = (unsigned short*)alloc((size_t)N_NODES * HC * 2);
    // total ~49 MB

    const int* esrc = edge_index;
    const int* edst = edge_index + N_EDGES;

    detect_kernel<<<1, 64, 0, stream>>>((const unsigned short*)x, flag);
    hipMemsetAsync(rcount, 0, N_REL * 4, stream);
    hipMemsetAsync(deg, 0, N_NODES * 4, stream);
    hipMemsetAsync(ea_mean, 0, F_DIM * 4, stream);
    hist_kernel<<<(N_EDGES + 255) / 256, 256, 0, stream>>>(edst, rel_index, deg, rcount);
    ea_mean_kernel<<<N_REL / 8, 256, 0, stream>>>(rcount, relations, ea_mean, flag);
    relext_kernel<<<(REL_EXT_ROWS * F_DIM + 255) / 256, 256, 0, stream>>>(relations, ea_mean, rel_ext, flag);
    scan_kernel<<<1, 1024, 0, stream>>>(deg, row_start, cursor);
    scatter_kernel<<<(N_EDGES + 255) / 256, 256, 0, stream>>>(esrc, edst, rel_index, cursor, csr_pack);
    w_transpose_kernel<<<dim3(2, 8, 12), 256, 0, stream>>>(Wl, Wr, We, Wt, flag);
    tail_kernel<<<(N_REL * F_DIM + 255) / 256, 256, 0, stream>>>(relations, d_out, flag);

    const void* hin = x;
    int a_input = 1;
    for (int l = 0; l < N_LAYERS; ++l) {
        const unsigned short* Wlt = Wt + (size_t)l * HC * F_DIM;
        const unsigned short* Wrt = Wt + (size_t)(4 + l) * HC * F_DIM;
        const unsigned short* Wet = Wt + (size_t)(8 + l) * HC * F_DIM;
        proj_kernel<<<dim3((N_NODES + 63) / 64, 4), 256, 0, stream>>>(
            hin, a_input, N_NODES, Wlt, Wrt,
            bl, (size_t)l * HC, br, (size_t)l * HC,
            xl, xr, 2, flag);
        proj_kernel<<<dim3((REL_EXT_ROWS + 63) / 64, 4), 256, 0, stream>>>(
            rel_ext, 0, REL_EXT_ROWS, Wet, nullptr,
            nullptr, 0, nullptr, 0,
            re, nullptr, 1, flag);
        int final_layer = (l == N_LAYERS - 1);
        void* hout = final_layer ? d_out : (void*)hbuf;
        edge_kernel<<<N_NODES, 256, 0, stream>>>(
            (const uint4*)xl, (const uint4*)xr, (const uint4*)re,
            row_start, csr_pack,
            att, (size_t)l * N_HEAD * F_DIM,
            bias, (size_t)l * F_DIM,
            hout, final_layer, flag);
        hin = hbuf;
        a_input = 0;
    }
}

// Round 11
// 585.723 us; speedup vs baseline: 1.5759x; 1.0610x over previous
//
#include <hip/hip_runtime.h>
#include <hip/hip_bf16.h>

#define N_NODES   20000
#define N_EDGES   100000
#define N_REL     1000
#define F_DIM     128
#define N_HEAD    4
#define HC        512      // N_HEAD * F_DIM
#define HC2       256      // HC/2 (bf16 pairs)
#define N_LAYERS  4
#define REL_EXT_ROWS 1008  // 1000 relations + 1 mean row
#define NEG_SLOPE 0.2f
#define NODE_MB   ((N_NODES + 63) / 64)      // 313
#define REL_MB    ((REL_EXT_ROWS + 63) / 64) // 16

typedef __attribute__((ext_vector_type(8))) short short8;
typedef __attribute__((ext_vector_type(4))) float floatx4;

__device__ __forceinline__ float loadIn(const void* p, size_t i, int f32) {
    if (f32) return ((const float*)p)[i];
    union { unsigned int u; float f; } c;
    c.u = ((unsigned int)((const unsigned short*)p)[i]) << 16;
    return c.f;
}

__device__ __forceinline__ unsigned short f2bf(float v) {
    __hip_bfloat16 b = __float2bfloat16(v);
    return *(unsigned short*)&b;
}

__device__ __forceinline__ void unpack2(unsigned int u, float& lo, float& hi) {
    union { unsigned int u; float f; } a, b;
    a.u = u << 16;
    b.u = u & 0xFFFF0000u;
    lo = a.f; hi = b.f;
}

// ---------------- dtype detection ----------------
__global__ void detect_kernel(const unsigned short* __restrict__ x, int* __restrict__ flag) {
    int t = threadIdx.x;  // 64
    int cnt = 0;
    for (int j = t; j < 256; j += 64) {
        int e = (x[j] >> 7) & 0xFF;
        if (e >= 143) cnt++;
    }
    for (int off = 32; off; off >>= 1) cnt += __shfl_xor(cnt, off);
    if (t == 0) flag[0] = (cnt >= 8) ? 1 : 0;
}

// ---------------- preprocessing ----------------

__global__ void hist_kernel(const int* __restrict__ dst, const int* __restrict__ rel,
                            int* __restrict__ deg, int* __restrict__ rcount) {
    int e = blockIdx.x * 256 + threadIdx.x;
    if (e < N_EDGES) {
        atomicAdd(&deg[dst[e]], 1);
        atomicAdd(&rcount[rel[e]], 1);
    }
}

__global__ void ea_mean_kernel(const int* __restrict__ rcount,
                               const void* __restrict__ relations,
                               float* __restrict__ ea_mean, const int* __restrict__ flag) {
    int f32 = flag[0];
    int b = blockIdx.x;
    int t = threadIdx.x;
    int col = t & 127;
    int rhalf = t >> 7;
    float acc = 0.f;
    for (int j = 0; j < 4; ++j) {
        int r = b * 8 + j * 2 + rhalf;
        acc += (float)rcount[r] * loadIn(relations, (size_t)r * F_DIM + col, f32);
    }
    __shared__ float part[256];
    part[t] = acc;
    __syncthreads();
    if (t < 128)
        atomicAdd(&ea_mean[col], (part[t] + part[t + 128]) * (1.f / (float)N_EDGES));
}

__global__ void relext_kernel(const void* __restrict__ relations,
                              const float* __restrict__ ea_mean,
                              unsigned short* __restrict__ rel_ext, const int* __restrict__ flag) {
    int idx = blockIdx.x * 256 + threadIdx.x;
    if (idx >= REL_EXT_ROWS * F_DIM) return;
    int f32 = flag[0];
    int r = idx >> 7;
    int c = idx & 127;
    float v;
    if (r < N_REL)       v = loadIn(relations, idx, f32);
    else if (r == N_REL) v = ea_mean[c];
    else                 v = 0.f;
    rel_ext[idx] = f2bf(v);
}

__global__ void scan_kernel(const int* __restrict__ deg,
                            int* __restrict__ row_start, int* __restrict__ cursor) {
    __shared__ int part[1024];
    int t = threadIdx.x;
    const int CH = (N_NODES + 1023) / 1024;  // 20
    int base = t * CH;
    int sum = 0;
    for (int j = 0; j < CH; ++j) {
        int idx = base + j;
        if (idx < N_NODES) sum += deg[idx];
    }
    part[t] = sum;
    __syncthreads();
    for (int off = 1; off < 1024; off <<= 1) {
        int u = (t >= off) ? part[t - off] : 0;
        __syncthreads();
        part[t] += u;
        __syncthreads();
    }
    int run = part[t] - sum;
    for (int j = 0; j < CH; ++j) {
        int idx = base + j;
        if (idx < N_NODES) {
            row_start[idx] = run;
            cursor[idx] = run;
            run += deg[idx];
        }
    }
    if (t == 1023) row_start[N_NODES] = part[1023];
}

__global__ void scatter_kernel(const int* __restrict__ src, const int* __restrict__ dst,
                               const int* __restrict__ rel, int* __restrict__ cursor,
                               int* __restrict__ csr_pack) {
    int e = blockIdx.x * 256 + threadIdx.x;
    if (e < N_EDGES) {
        int d = dst[e];
        int p = atomicAdd(&cursor[d], 1);
        csr_pack[p] = src[e] | (rel[e] << 16);
    }
}

__global__ void tail_kernel(const void* __restrict__ relations, void* __restrict__ out,
                            const int* __restrict__ flag) {
    int i = blockIdx.x * 256 + threadIdx.x;
    if (i >= N_REL * F_DIM) return;
    int f32 = flag[0];
    float v = loadIn(relations, i, f32);
    size_t o = (size_t)N_NODES * F_DIM + i;
    if (f32) ((float*)out)[o] = v;
    else     ((unsigned short*)out)[o] = f2bf(v);
}

// ---------------- weight transpose: W[l][128 k][512 n] -> Wt[mat][512 n][128 k] bf16 ----------------
__global__ void w_transpose_kernel(const void* __restrict__ Wl, const void* __restrict__ Wr,
                                   const void* __restrict__ We,
                                   unsigned short* __restrict__ Wt, const int* __restrict__ flag) {
    int f32 = flag[0];
    int k0 = blockIdx.x * 64;
    int n0 = blockIdx.y * 64;
    int mat = blockIdx.z;
    const void* src = (mat < 4) ? Wl : (mat < 8 ? Wr : We);
    size_t base = (size_t)(mat & 3) * F_DIM * HC;
    unsigned short* dst = Wt + (size_t)mat * HC * F_DIM;
    __shared__ float T[64][65];
    int t = threadIdx.x;
    int r = t >> 2, cq = t & 3;
    for (int j = 0; j < 16; ++j) {
        int n = cq * 16 + j;
        T[n][r] = loadIn(src, base + (size_t)(k0 + r) * HC + n0 + n, f32);
    }
    __syncthreads();
    for (int j = 0; j < 16; ++j) {
        int k = cq * 16 + j;
        dst[(size_t)(n0 + r) * F_DIM + k0 + k] = f2bf(T[r][k]);
    }
}

// ---------------- merged projection GEMM (node + rel in one launch) ----------------
// grid (NODE_MB + REL_MB, 4). Blocks [0,NODE_MB): node rows, tpb=2 tiles
// (y*2+it; nt<4 -> Wl/bl/xl else Wr/br/xr). Blocks [NODE_MB,..): rel rows,
// 1 tile (nt=y), We -> re, no bias.
__launch_bounds__(256, 4)
__global__ void proj_kernel(const void* __restrict__ A_node, int a_input,
                            const unsigned short* __restrict__ rel_ext,
                            const unsigned short* __restrict__ Wlt,
                            const unsigned short* __restrict__ Wrt,
                            const unsigned short* __restrict__ Wet,
                            const void* __restrict__ bl, const void* __restrict__ br,
                            size_t boff,
                            unsigned short* __restrict__ xl,
                            unsigned short* __restrict__ xr,
                            unsigned short* __restrict__ re,
                            const int* __restrict__ flag) {
    __shared__ __align__(16) short As[64][136];    // 17.4 KB
    __shared__ __align__(16) short BtRaw[128 * 72];// 18.4 KB; Cs view: stride 136
    int f32 = flag[0];
    int isNode = (blockIdx.x < NODE_MB);
    int m0 = (isNode ? blockIdx.x : (blockIdx.x - NODE_MB)) * 64;
    int M = isNode ? N_NODES : REL_EXT_ROWS;
    int tpb = isNode ? 2 : 1;
    int a_f32 = (isNode && a_input) ? f32 : 0;
    const void* A = isNode ? A_node : (const void*)rel_ext;
    int t = threadIdx.x;

    // stage A once: 64 rows x 128 K (short8 chunks)
    for (int j = 0; j < 4; ++j) {
        int c = t + j * 256;
        int row = c >> 4;
        int colc = (c & 15) * 8;
        int gm = m0 + row;
        short8 v = (short8){0, 0, 0, 0, 0, 0, 0, 0};
        if (gm < M) {
            size_t idx = (size_t)gm * F_DIM + colc;
            if (a_f32) {
                const float* Af = (const float*)A;
                for (int q = 0; q < 8; ++q) v[q] = (short)f2bf(Af[idx + q]);
            } else {
                v = *(const short8*)((const unsigned short*)A + idx);
            }
        }
        *(short8*)&As[row][colc] = v;
    }

    int wave = t >> 6, lane = t & 63;
    int wm = (wave >> 1) * 32, wn = (wave & 1) * 64;
    int r16 = lane & 15, quad = lane >> 4;

    for (int it = 0; it < tpb; ++it) {
        int nt = isNode ? (blockIdx.y * 2 + it) : blockIdx.y;
        const unsigned short* Wt = isNode ? ((nt < 4) ? Wlt : Wrt) : Wet;
        int n0 = (nt & 3) * 128;

        floatx4 acc[2][4];
        for (int mi = 0; mi < 2; ++mi)
            for (int ni = 0; ni < 4; ++ni)
                acc[mi][ni] = (floatx4){0.f, 0.f, 0.f, 0.f};

        for (int half = 0; half < 2; ++half) {
            __syncthreads();
            for (int j = 0; j < 4; ++j) {
                int c = t + j * 256;
                int nl = c >> 3;
                int kc = (c & 7) * 8;
                *(short8*)&BtRaw[nl * 72 + kc] =
                    *(const short8*)(Wt + (size_t)(n0 + nl) * F_DIM + half * 64 + kc);
            }
            __syncthreads();

            for (int kk = 0; kk < 2; ++kk) {
                short8 a[2], b[4];
                for (int mi = 0; mi < 2; ++mi)
                    a[mi] = *(const short8*)&As[wm + mi * 16 + r16][half * 64 + kk * 32 + quad * 8];
                for (int ni = 0; ni < 4; ++ni)
                    b[ni] = *(const short8*)&BtRaw[(wn + ni * 16 + r16) * 72 + kk * 32 + quad * 8];
                for (int mi = 0; mi < 2; ++mi)
                    for (int ni = 0; ni < 4; ++ni)
                        acc[mi][ni] = __builtin_amdgcn_mfma_f32_16x16x32_bf16(a[mi], b[ni], acc[mi][ni], 0, 0, 0);
            }
        }

        const void* bias = isNode ? ((nt < 4) ? bl : br) : nullptr;
        unsigned short* out = isNode ? ((nt < 4) ? xl : xr) : re;
        __syncthreads();
        for (int mi = 0; mi < 2; ++mi) {
            for (int ni = 0; ni < 4; ++ni) {
                int col = wn + ni * 16 + r16;
                float bv = bias ? loadIn(bias, boff + n0 + col, f32) : 0.f;
                for (int r = 0; r < 4; ++r) {
                    int rowl = wm + mi * 16 + quad * 4 + r;
                    BtRaw[rowl * 136 + col] = (short)f2bf(acc[mi][ni][r] + bv);
                }
            }
        }
        __syncthreads();
        for (int j = 0; j < 4; ++j) {
            int c = t + j * 256;
            int rowl = c >> 4;
            int colc = (c & 15) * 8;
            int gm = m0 + rowl;
            if (gm < M)
                *(short8*)(out + (size_t)gm * HC + n0 + colc) =
                    *(const short8*)&BtRaw[rowl * 136 + colc];
        }
    }
}

// ---------------- edge kernel: full-row waves, edge-parallel, no-max softmax, prefetch ----------------
// One block per dst node. Wave owns the full 512-ch row (lane = channels [lane*8, lane*8+8),
// head = lane>>4), slots slot%4==w. Slot 0 = self-loop (mean rel row).
// 1-deep value prefetch: next slot's xl/re rows are loaded before computing the current slot
// (MLP — this was the r7-vs-r10 60->93 µs delta). No-max clamped-exp softmax (slots independent).
__launch_bounds__(256)
__global__ void edge_kernel(const uint4* __restrict__ xl4,
                            const uint4* __restrict__ xr4,
                            const uint4* __restrict__ re4,
                            const int* __restrict__ row_start,
                            const int* __restrict__ csr_pack,
                            const void* __restrict__ att, size_t att_off,
                            const void* __restrict__ bias, size_t bias_off,
                            void* __restrict__ hout, int final_layer,
                            const int* __restrict__ flag) {
    __shared__ float lacc[N_HEAD][HC];      // [wave][512] partials, 8 KB
    __shared__ float sW[N_HEAD][N_HEAD];    // [wave][head] partial sums

    int f32 = flag[0];
    int i = blockIdx.x;
    int t = threadIdx.x, w = t >> 6, lane = t & 63;

    float xrv[8], attv[8];
    {
        uint4 u = xr4[(size_t)i * 64 + lane];
        unpack2(u.x, xrv[0], xrv[1]); unpack2(u.y, xrv[2], xrv[3]);
        unpack2(u.z, xrv[4], xrv[5]); unpack2(u.w, xrv[6], xrv[7]);
        for (int q = 0; q < 8; ++q)
            attv[q] = loadIn(att, att_off + lane * 8 + q, f32);
    }

    int e0 = row_start[i], e1 = row_start[i + 1];
    if (e0 < 0) e0 = 0;
    if (e1 > N_EDGES) e1 = N_EDGES;
    if (e1 < e0) e1 = e0;
    int total = (e1 - e0) + 1;   // + self-loop at slot 0

    float s = 0.f;
    float acc[8];
    for (int q = 0; q < 8; ++q) acc[q] = 0.f;

    int slot = w;
    uint4 xu = (uint4){0, 0, 0, 0}, ru = (uint4){0, 0, 0, 0};
    if (slot < total) {
        int src, rr;
        if (slot == 0) { src = i; rr = N_REL; }
        else {
            int pk = csr_pack[e0 + slot - 1];
            src = pk & 0xFFFF;        if (src >= N_NODES) src = 0;
            rr  = (pk >> 16) & 0x3FF; if (rr > N_REL) rr = N_REL;
        }
        xu = xl4[(size_t)src * 64 + lane];
        ru = re4[(size_t)rr * 64 + lane];
    }
    while (slot < total) {
        int nslot = slot + 4;
        uint4 xc = xu, rc = ru;
        if (nslot < total) {   // prefetch next slot's rows (nslot >= 4 > 0)
            int pk = csr_pack[e0 + nslot - 1];
            int src = pk & 0xFFFF;        if (src >= N_NODES) src = 0;
            int rr  = (pk >> 16) & 0x3FF; if (rr > N_REL) rr = N_REL;
            xu = xl4[(size_t)src * 64 + lane];
            ru = re4[(size_t)rr * 64 + lane];
        }
        float xv[8], rv[8];
        unpack2(xc.x, xv[0], xv[1]); unpack2(xc.y, xv[2], xv[3]);
        unpack2(xc.z, xv[4], xv[5]); unpack2(xc.w, xv[6], xv[7]);
        unpack2(rc.x, rv[0], rv[1]); unpack2(rc.y, rv[2], rv[3]);
        unpack2(rc.z, rv[4], rv[5]); unpack2(rc.w, rv[6], rv[7]);
        float part = 0.f;
        for (int q = 0; q < 8; ++q) {
            float u = xv[q] + xrv[q] + rv[q];
            u = fmaxf(u, NEG_SLOPE * u);   // leaky_relu
            part += u * attv[q];
        }
        for (int off = 8; off; off >>= 1) part += __shfl_xor(part, off);
        part = fminf(fmaxf(part, -60.f), 60.f);
        float p = __expf(part);
        s += p;
        for (int q = 0; q < 8; ++q) acc[q] += p * xv[q];
        slot = nslot;
    }

    // merge 4 wave partials
    for (int q = 0; q < 8; ++q) lacc[w][lane * 8 + q] = acc[q];
    if ((lane & 15) == 0) sW[w][lane >> 4] = s;
    __syncthreads();
    if (t < F_DIM) {
        int c = t;
        float v = 0.f;
        for (int h = 0; h < N_HEAD; ++h) {
            float S = sW[0][h] + sW[1][h] + sW[2][h] + sW[3][h];
            float a = lacc[0][h * F_DIM + c] + lacc[1][h * F_DIM + c]
                    + lacc[2][h * F_DIM + c] + lacc[3][h * F_DIM + c];
            v += a / S;
        }
        v = v * 0.25f + loadIn(bias, bias_off + c, f32);
        size_t o = (size_t)i * F_DIM + c;
        if (final_layer && f32) ((float*)hout)[o] = v;
        else                    ((unsigned short*)hout)[o] = f2bf(v);
    }
}

// ---------------- launch ----------------

extern "C" void kernel_launch(void* const* d_in, const int* in_sizes, int n_in,
                              void* d_out, int out_size, void* d_ws, size_t ws_size,
                              hipStream_t stream) {
    const void* x          = d_in[0];
    const int*  edge_index = (const int*)d_in[1];
    const void* relations  = d_in[2];
    const int*  rel_index  = (const int*)d_in[3];
    const void* Wl         = d_in[4];
    const void* bl         = d_in[5];
    const void* Wr         = d_in[6];
    const void* br         = d_in[7];
    const void* We         = d_in[8];
    const void* att        = d_in[9];
    const void* bias       = d_in[10];

    char* ws = (char*)d_ws;
    size_t off = 0;
    auto alloc = [&](size_t bytes) -> void* {
        void* p = ws + off;
        off = (off + bytes + 255) & ~(size_t)255;
        return p;
    };
    int*            flag     = (int*)alloc(4);
    int*            deg      = (int*)alloc(N_NODES * 4);
    int*            row_start= (int*)alloc((N_NODES + 1) * 4);
    int*            cursor   = (int*)alloc(N_NODES * 4);
    int*            rcount   = (int*)alloc(N_REL * 4);
    float*          ea_mean  = (float*)alloc(F_DIM * 4);
    int*            csr_pack = (int*)alloc(N_EDGES * 4);
    unsigned short* rel_ext  = (unsigned short*)alloc((size_t)REL_EXT_ROWS * F_DIM * 2);
    unsigned short* Wt       = (unsigned short*)alloc((size_t)12 * HC * F_DIM * 2);  // 1.57 MB
    unsigned short* re       = (unsigned short*)alloc((size_t)REL_EXT_ROWS * HC * 2);
    unsigned short* hbuf     = (unsigned short*)alloc((size_t)N_NODES * F_DIM * 2);
    unsigned short* xl       = (unsigned short*)alloc((size_t)N_NODES * HC * 2);
    unsigned short* xr       = (unsigned short*)alloc((size_t)N_NODES * HC * 2);
    // total ~49 MB

    const int* esrc = edge_index;
    const int* edst = edge_index + N_EDGES;

    detect_kernel<<<1, 64, 0, stream>>>((const unsigned short*)x, flag);
    hipMemsetAsync(rcount, 0, N_REL * 4, stream);
    hipMemsetAsync(deg, 0, N_NODES * 4, stream);
    hipMemsetAsync(ea_mean, 0, F_DIM * 4, stream);
    hist_kernel<<<(N_EDGES + 255) / 256, 256, 0, stream>>>(edst, rel_index, deg, rcount);
    ea_mean_kernel<<<N_REL / 8, 256, 0, stream>>>(rcount, relations, ea_mean, flag);
    relext_kernel<<<(REL_EXT_ROWS * F_DIM + 255) / 256, 256, 0, stream>>>(relations, ea_mean, rel_ext, flag);
    scan_kernel<<<1, 1024, 0, stream>>>(deg, row_start, cursor);
    scatter_kernel<<<(N_EDGES + 255) / 256, 256, 0, stream>>>(esrc, edst, rel_index, cursor, csr_pack);
    w_transpose_kernel<<<dim3(2, 8, 12), 256, 0, stream>>>(Wl, Wr, We, Wt, flag);
    tail_kernel<<<(N_REL * F_DIM + 255) / 256, 256, 0, stream>>>(relations, d_out, flag);

    const void* hin = x;
    int a_input = 1;
    for (int l = 0; l < N_LAYERS; ++l) {
        const unsigned short* Wlt = Wt + (size_t)l * HC * F_DIM;
        const unsigned short* Wrt = Wt + (size_t)(4 + l) * HC * F_DIM;
        const unsigned short* Wet = Wt + (size_t)(8 + l) * HC * F_DIM;
        // merged node+rel projection: 329 x 4 blocks
        proj_kernel<<<dim3(NODE_MB + REL_MB, 4), 256, 0, stream>>>(
            hin, a_input, rel_ext, Wlt, Wrt, Wet,
            bl, br, (size_t)l * HC,
            xl, xr, re, flag);
        int final_layer = (l == N_LAYERS - 1);
        void* hout = final_layer ? d_out : (void*)hbuf;
        edge_kernel<<<N_NODES, 256, 0, stream>>>(
            (const uint4*)xl, (const uint4*)xr, (const uint4*)re,
            row_start, csr_pack,
            att, (size_t)l * N_HEAD * F_DIM,
            bias, (size_t)l * F_DIM,
            hout, final_layer, flag);
        hin = hbuf;
        a_input = 0;
    }
}

// Round 12
// 465.944 us; speedup vs baseline: 1.9811x; 1.2571x over previous
//
#include <hip/hip_runtime.h>
#include <hip/hip_bf16.h>

#define N_NODES   20000
#define N_EDGES   100000
#define N_REL     1000
#define F_DIM     128
#define N_HEAD    4
#define HC        512      // N_HEAD * F_DIM
#define HC2       256      // HC/2 (bf16 pairs)
#define N_LAYERS  4
#define REL_EXT_ROWS 1008  // 1000 relations + 1 mean row
#define NEG_SLOPE 0.2f
#define NODE_MB   ((N_NODES + 63) / 64)      // 313
#define REL_MB    ((REL_EXT_ROWS + 63) / 64) // 16

typedef __attribute__((ext_vector_type(8))) short short8;
typedef __attribute__((ext_vector_type(4))) float floatx4;

__device__ __forceinline__ float loadIn(const void* p, size_t i, int f32) {
    if (f32) return ((const float*)p)[i];
    union { unsigned int u; float f; } c;
    c.u = ((unsigned int)((const unsigned short*)p)[i]) << 16;
    return c.f;
}

__device__ __forceinline__ unsigned short f2bf(float v) {
    __hip_bfloat16 b = __float2bfloat16(v);
    return *(unsigned short*)&b;
}

__device__ __forceinline__ void unpack2(unsigned int u, float& lo, float& hi) {
    union { unsigned int u; float f; } a, b;
    a.u = u << 16;
    b.u = u & 0xFFFF0000u;
    lo = a.f; hi = b.f;
}

// ---------------- dtype detection ----------------
__global__ void detect_kernel(const unsigned short* __restrict__ x, int* __restrict__ flag) {
    int t = threadIdx.x;  // 64
    int cnt = 0;
    for (int j = t; j < 256; j += 64) {
        int e = (x[j] >> 7) & 0xFF;
        if (e >= 143) cnt++;
    }
    for (int off = 32; off; off >>= 1) cnt += __shfl_xor(cnt, off);
    if (t == 0) flag[0] = (cnt >= 8) ? 1 : 0;
}

// ---------------- preprocessing ----------------

__global__ void hist_kernel(const int* __restrict__ dst, const int* __restrict__ rel,
                            int* __restrict__ deg, int* __restrict__ rcount) {
    int e = blockIdx.x * 256 + threadIdx.x;
    if (e < N_EDGES) {
        atomicAdd(&deg[dst[e]], 1);
        atomicAdd(&rcount[rel[e]], 1);
    }
}

__global__ void ea_mean_kernel(const int* __restrict__ rcount,
                               const void* __restrict__ relations,
                               float* __restrict__ ea_mean, const int* __restrict__ flag) {
    int f32 = flag[0];
    int b = blockIdx.x;
    int t = threadIdx.x;
    int col = t & 127;
    int rhalf = t >> 7;
    float acc = 0.f;
    for (int j = 0; j < 4; ++j) {
        int r = b * 8 + j * 2 + rhalf;
        acc += (float)rcount[r] * loadIn(relations, (size_t)r * F_DIM + col, f32);
    }
    __shared__ float part[256];
    part[t] = acc;
    __syncthreads();
    if (t < 128)
        atomicAdd(&ea_mean[col], (part[t] + part[t + 128]) * (1.f / (float)N_EDGES));
}

__global__ void relext_kernel(const void* __restrict__ relations,
                              const float* __restrict__ ea_mean,
                              unsigned short* __restrict__ rel_ext, const int* __restrict__ flag) {
    int idx = blockIdx.x * 256 + threadIdx.x;
    if (idx >= REL_EXT_ROWS * F_DIM) return;
    int f32 = flag[0];
    int r = idx >> 7;
    int c = idx & 127;
    float v;
    if (r < N_REL)       v = loadIn(relations, idx, f32);
    else if (r == N_REL) v = ea_mean[c];
    else                 v = 0.f;
    rel_ext[idx] = f2bf(v);
}

__global__ void scan_kernel(const int* __restrict__ deg,
                            int* __restrict__ row_start, int* __restrict__ cursor) {
    __shared__ int part[1024];
    int t = threadIdx.x;
    const int CH = (N_NODES + 1023) / 1024;  // 20
    int base = t * CH;
    int sum = 0;
    for (int j = 0; j < CH; ++j) {
        int idx = base + j;
        if (idx < N_NODES) sum += deg[idx];
    }
    part[t] = sum;
    __syncthreads();
    for (int off = 1; off < 1024; off <<= 1) {
        int u = (t >= off) ? part[t - off] : 0;
        __syncthreads();
        part[t] += u;
        __syncthreads();
    }
    int run = part[t] - sum;
    for (int j = 0; j < CH; ++j) {
        int idx = base + j;
        if (idx < N_NODES) {
            row_start[idx] = run;
            cursor[idx] = run;
            run += deg[idx];
        }
    }
    if (t == 1023) row_start[N_NODES] = part[1023];
}

__global__ void scatter_kernel(const int* __restrict__ src, const int* __restrict__ dst,
                               const int* __restrict__ rel, int* __restrict__ cursor,
                               int* __restrict__ csr_pack) {
    int e = blockIdx.x * 256 + threadIdx.x;
    if (e < N_EDGES) {
        int d = dst[e];
        int p = atomicAdd(&cursor[d], 1);
        csr_pack[p] = src[e] | (rel[e] << 16);
    }
}

__global__ void tail_kernel(const void* __restrict__ relations, void* __restrict__ out,
                            const int* __restrict__ flag) {
    int i = blockIdx.x * 256 + threadIdx.x;
    if (i >= N_REL * F_DIM) return;
    int f32 = flag[0];
    float v = loadIn(relations, i, f32);
    size_t o = (size_t)N_NODES * F_DIM + i;
    if (f32) ((float*)out)[o] = v;
    else     ((unsigned short*)out)[o] = f2bf(v);
}

// ---------------- weight transpose: W[l][128 k][512 n] -> Wt[mat][512 n][128 k] bf16 ----------------
__global__ void w_transpose_kernel(const void* __restrict__ Wl, const void* __restrict__ Wr,
                                   const void* __restrict__ We,
                                   unsigned short* __restrict__ Wt, const int* __restrict__ flag) {
    int f32 = flag[0];
    int k0 = blockIdx.x * 64;
    int n0 = blockIdx.y * 64;
    int mat = blockIdx.z;
    const void* src = (mat < 4) ? Wl : (mat < 8 ? Wr : We);
    size_t base = (size_t)(mat & 3) * F_DIM * HC;
    unsigned short* dst = Wt + (size_t)mat * HC * F_DIM;
    __shared__ float T[64][65];
    int t = threadIdx.x;
    int r = t >> 2, cq = t & 3;
    for (int j = 0; j < 16; ++j) {
        int n = cq * 16 + j;
        T[n][r] = loadIn(src, base + (size_t)(k0 + r) * HC + n0 + n, f32);
    }
    __syncthreads();
    for (int j = 0; j < 16; ++j) {
        int k = cq * 16 + j;
        dst[(size_t)(n0 + r) * F_DIM + k0 + k] = f2bf(T[r][k]);
    }
}

// ---------------- merged projection GEMM (node + rel in one launch) ----------------
__launch_bounds__(256, 4)
__global__ void proj_kernel(const void* __restrict__ A_node, int a_input,
                            const unsigned short* __restrict__ rel_ext,
                            const unsigned short* __restrict__ Wlt,
                            const unsigned short* __restrict__ Wrt,
                            const unsigned short* __restrict__ Wet,
                            const void* __restrict__ bl, const void* __restrict__ br,
                            size_t boff,
                            unsigned short* __restrict__ xl,
                            unsigned short* __restrict__ xr,
                            unsigned short* __restrict__ re,
                            const int* __restrict__ flag) {
    __shared__ __align__(16) short As[64][136];    // 17.4 KB
    __shared__ __align__(16) short BtRaw[128 * 72];// 18.4 KB; Cs view: stride 136
    int f32 = flag[0];
    int isNode = (blockIdx.x < NODE_MB);
    int m0 = (isNode ? blockIdx.x : (blockIdx.x - NODE_MB)) * 64;
    int M = isNode ? N_NODES : REL_EXT_ROWS;
    int tpb = isNode ? 2 : 1;
    int a_f32 = (isNode && a_input) ? f32 : 0;
    const void* A = isNode ? A_node : (const void*)rel_ext;
    int t = threadIdx.x;

    for (int j = 0; j < 4; ++j) {
        int c = t + j * 256;
        int row = c >> 4;
        int colc = (c & 15) * 8;
        int gm = m0 + row;
        short8 v = (short8){0, 0, 0, 0, 0, 0, 0, 0};
        if (gm < M) {
            size_t idx = (size_t)gm * F_DIM + colc;
            if (a_f32) {
                const float* Af = (const float*)A;
                for (int q = 0; q < 8; ++q) v[q] = (short)f2bf(Af[idx + q]);
            } else {
                v = *(const short8*)((const unsigned short*)A + idx);
            }
        }
        *(short8*)&As[row][colc] = v;
    }

    int wave = t >> 6, lane = t & 63;
    int wm = (wave >> 1) * 32, wn = (wave & 1) * 64;
    int r16 = lane & 15, quad = lane >> 4;

    for (int it = 0; it < tpb; ++it) {
        int nt = isNode ? (blockIdx.y * 2 + it) : blockIdx.y;
        const unsigned short* Wt = isNode ? ((nt < 4) ? Wlt : Wrt) : Wet;
        int n0 = (nt & 3) * 128;

        floatx4 acc[2][4];
        for (int mi = 0; mi < 2; ++mi)
            for (int ni = 0; ni < 4; ++ni)
                acc[mi][ni] = (floatx4){0.f, 0.f, 0.f, 0.f};

        for (int half = 0; half < 2; ++half) {
            __syncthreads();
            for (int j = 0; j < 4; ++j) {
                int c = t + j * 256;
                int nl = c >> 3;
                int kc = (c & 7) * 8;
                *(short8*)&BtRaw[nl * 72 + kc] =
                    *(const short8*)(Wt + (size_t)(n0 + nl) * F_DIM + half * 64 + kc);
            }
            __syncthreads();

            for (int kk = 0; kk < 2; ++kk) {
                short8 a[2], b[4];
                for (int mi = 0; mi < 2; ++mi)
                    a[mi] = *(const short8*)&As[wm + mi * 16 + r16][half * 64 + kk * 32 + quad * 8];
                for (int ni = 0; ni < 4; ++ni)
                    b[ni] = *(const short8*)&BtRaw[(wn + ni * 16 + r16) * 72 + kk * 32 + quad * 8];
                for (int mi = 0; mi < 2; ++mi)
                    for (int ni = 0; ni < 4; ++ni)
                        acc[mi][ni] = __builtin_amdgcn_mfma_f32_16x16x32_bf16(a[mi], b[ni], acc[mi][ni], 0, 0, 0);
            }
        }

        const void* bias = isNode ? ((nt < 4) ? bl : br) : nullptr;
        unsigned short* out = isNode ? ((nt < 4) ? xl : xr) : re;
        __syncthreads();
        for (int mi = 0; mi < 2; ++mi) {
            for (int ni = 0; ni < 4; ++ni) {
                int col = wn + ni * 16 + r16;
                float bv = bias ? loadIn(bias, boff + n0 + col, f32) : 0.f;
                for (int r = 0; r < 4; ++r) {
                    int rowl = wm + mi * 16 + quad * 4 + r;
                    BtRaw[rowl * 136 + col] = (short)f2bf(acc[mi][ni][r] + bv);
                }
            }
        }
        __syncthreads();
        for (int j = 0; j < 4; ++j) {
            int c = t + j * 256;
            int rowl = c >> 4;
            int colc = (c & 15) * 8;
            int gm = m0 + rowl;
            if (gm < M)
                *(short8*)(out + (size_t)gm * HC + n0 + colc) =
                    *(const short8*)&BtRaw[rowl * 136 + colc];
        }
    }
}

// ---------------- edge kernel: r7 structure (measured 60 us) + no-max clamped-exp softmax ----------------
// One block per dst node; wave h = head h; ALL waves walk ALL edges (long per-wave loop
// = real pipelining); lane owns channels (2*lane, 2*lane+1); 1-deep value prefetch.
// No-max softmax: p = exp(clamp(logit)); removes the per-edge online-rescale dependent chain.
__launch_bounds__(256)
__global__ void edge_kernel(const unsigned int* __restrict__ xl2,
                            const unsigned int* __restrict__ xr2,
                            const unsigned int* __restrict__ re2,
                            const int* __restrict__ row_start,
                            const int* __restrict__ csr_pack,
                            const void* __restrict__ att, size_t att_off,
                            const void* __restrict__ bias, size_t bias_off,
                            void* __restrict__ hout, int final_layer,
                            const int* __restrict__ flag) {
    int f32 = flag[0];
    int i = blockIdx.x;
    int h = threadIdx.x >> 6;
    int lane = threadIdx.x & 63;
    int pidx = h * 64 + lane;

    float xr0, xr1; unpack2(xr2[(size_t)i * HC2 + pidx], xr0, xr1);
    float a0 = loadIn(att, att_off + h * F_DIM + 2 * lane, f32);
    float a1 = loadIn(att, att_off + h * F_DIM + 2 * lane + 1, f32);
    float er0, er1; unpack2(re2[(size_t)N_REL * HC2 + pidx], er0, er1);

    // self-loop first (seed)
    float xs0, xs1; unpack2(xl2[(size_t)i * HC2 + pidx], xs0, xs1);
    float t0 = xs0 + xr0 + er0;
    float t1 = xs1 + xr1 + er1;
    t0 = fmaxf(t0, NEG_SLOPE * t0);
    t1 = fmaxf(t1, NEG_SLOPE * t1);
    float part = t0 * a0 + t1 * a1;
    for (int off = 32; off; off >>= 1) part += __shfl_xor(part, off);
    part = fminf(fmaxf(part, -60.f), 60.f);
    float p = __expf(part);
    float s = p, acc0 = p * xs0, acc1 = p * xs1;

    int e0 = row_start[i], e1 = row_start[i + 1];
    if (e0 < 0) e0 = 0;
    if (e1 > N_EDGES) e1 = N_EDGES;
    if (e1 < e0) e1 = e0;

    unsigned int xlv = 0, rev = 0;
    if (e0 < e1) {
        int pk = csr_pack[e0];
        int src = pk & 0xFFFF;  if (src >= N_NODES) src = 0;
        int rr  = (pk >> 16) & 0x3FF; if (rr > N_REL) rr = N_REL;
        xlv = xl2[(size_t)src * HC2 + pidx];
        rev = re2[(size_t)rr * HC2 + pidx];
    }
    for (int e = e0; e < e1; ++e) {
        unsigned int xlvn = 0, revn = 0;
        if (e + 1 < e1) {   // 1-deep value prefetch
            int pkn = csr_pack[e + 1];
            int sn = pkn & 0xFFFF;  if (sn >= N_NODES) sn = 0;
            int rn = (pkn >> 16) & 0x3FF; if (rn > N_REL) rn = N_REL;
            xlvn = xl2[(size_t)sn * HC2 + pidx];
            revn = re2[(size_t)rn * HC2 + pidx];
        }
        float xl0, xl1; unpack2(xlv, xl0, xl1);
        float ee0, ee1; unpack2(rev, ee0, ee1);
        float u0 = xl0 + xr0 + ee0;
        float u1 = xl1 + xr1 + ee1;
        u0 = fmaxf(u0, NEG_SLOPE * u0);
        u1 = fmaxf(u1, NEG_SLOPE * u1);
        float pe = u0 * a0 + u1 * a1;
        for (int off = 32; off; off >>= 1) pe += __shfl_xor(pe, off);
        pe = fminf(fmaxf(pe, -60.f), 60.f);
        float pp = __expf(pe);
        s += pp;
        acc0 += pp * xl0;
        acc1 += pp * xl1;
        xlv = xlvn; rev = revn;
    }

    float inv = 1.f / s;
    __shared__ float lsum[N_HEAD][F_DIM];
    lsum[h][2 * lane]     = acc0 * inv;
    lsum[h][2 * lane + 1] = acc1 * inv;
    __syncthreads();
    if (threadIdx.x < F_DIM) {
        int c = threadIdx.x;
        float v = (lsum[0][c] + lsum[1][c] + lsum[2][c] + lsum[3][c]) * 0.25f
                + loadIn(bias, bias_off + c, f32);
        size_t o = (size_t)i * F_DIM + c;
        if (final_layer && f32) ((float*)hout)[o] = v;
        else                    ((unsigned short*)hout)[o] = f2bf(v);
    }
}

// ---------------- launch ----------------

extern "C" void kernel_launch(void* const* d_in, const int* in_sizes, int n_in,
                              void* d_out, int out_size, void* d_ws, size_t ws_size,
                              hipStream_t stream) {
    const void* x          = d_in[0];
    const int*  edge_index = (const int*)d_in[1];
    const void* relations  = d_in[2];
    const int*  rel_index  = (const int*)d_in[3];
    const void* Wl         = d_in[4];
    const void* bl         = d_in[5];
    const void* Wr         = d_in[6];
    const void* br         = d_in[7];
    const void* We         = d_in[8];
    const void* att        = d_in[9];
    const void* bias       = d_in[10];

    char* ws = (char*)d_ws;
    size_t off = 0;
    auto alloc = [&](size_t bytes) -> void* {
        void* p = ws + off;
        off = (off + bytes + 255) & ~(size_t)255;
        return p;
    };
    int*            flag     = (int*)alloc(4);
    int*            deg      = (int*)alloc(N_NODES * 4);
    int*            row_start= (int*)alloc((N_NODES + 1) * 4);
    int*            cursor   = (int*)alloc(N_NODES * 4);
    int*            rcount   = (int*)alloc(N_REL * 4);
    float*          ea_mean  = (float*)alloc(F_DIM * 4);
    int*            csr_pack = (int*)alloc(N_EDGES * 4);
    unsigned short* rel_ext  = (unsigned short*)alloc((size_t)REL_EXT_ROWS * F_DIM * 2);
    unsigned short* Wt       = (unsigned short*)alloc((size_t)12 * HC * F_DIM * 2);  // 1.57 MB
    unsigned short* re       = (unsigned short*)alloc((size_t)REL_EXT_ROWS * HC * 2);
    unsigned short* hbuf     = (unsigned short*)alloc((size_t)N_NODES * F_DIM * 2);
    unsigned short* xl       = (unsigned short*)alloc((size_t)N_NODES * HC * 2);
    unsigned short* xr       = (unsigned short*)alloc((size_t)N_NODES * HC * 2);
    // total ~49 MB

    const int* esrc = edge_index;
    const int* edst = edge_index + N_EDGES;

    detect_kernel<<<1, 64, 0, stream>>>((const unsigned short*)x, flag);
    hipMemsetAsync(rcount, 0, N_REL * 4, stream);
    hipMemsetAsync(deg, 0, N_NODES * 4, stream);
    hipMemsetAsync(ea_mean, 0, F_DIM * 4, stream);
    hist_kernel<<<(N_EDGES + 255) / 256, 256, 0, stream>>>(edst, rel_index, deg, rcount);
    ea_mean_kernel<<<N_REL / 8, 256, 0, stream>>>(rcount, relations, ea_mean, flag);
    relext_kernel<<<(REL_EXT_ROWS * F_DIM + 255) / 256, 256, 0, stream>>>(relations, ea_mean, rel_ext, flag);
    scan_kernel<<<1, 1024, 0, stream>>>(deg, row_start, cursor);
    scatter_kernel<<<(N_EDGES + 255) / 256, 256, 0, stream>>>(esrc, edst, rel_index, cursor, csr_pack);
    w_transpose_kernel<<<dim3(2, 8, 12), 256, 0, stream>>>(Wl, Wr, We, Wt, flag);
    tail_kernel<<<(N_REL * F_DIM + 255) / 256, 256, 0, stream>>>(relations, d_out, flag);

    const void* hin = x;
    int a_input = 1;
    for (int l = 0; l < N_LAYERS; ++l) {
        const unsigned short* Wlt = Wt + (size_t)l * HC * F_DIM;
        const unsigned short* Wrt = Wt + (size_t)(4 + l) * HC * F_DIM;
        const unsigned short* Wet = Wt + (size_t)(8 + l) * HC * F_DIM;
        // merged node+rel projection: 329 x 4 blocks
        proj_kernel<<<dim3(NODE_MB + REL_MB, 4), 256, 0, stream>>>(
            hin, a_input, rel_ext, Wlt, Wrt, Wet,
            bl, br, (size_t)l * HC,
            xl, xr, re, flag);
        int final_layer = (l == N_LAYERS - 1);
        void* hout = final_layer ? d_out : (void*)hbuf;
        edge_kernel<<<N_NODES, 256, 0, stream>>>(
            (const unsigned int*)xl, (const unsigned int*)xr, (const unsigned int*)re,
            row_start, csr_pack,
            att, (size_t)l * N_HEAD * F_DIM,
            bias, (size_t)l * F_DIM,
            hout, final_layer, flag);
        hin = hbuf;
        a_input = 0;
    }
}

// Round 13
// 438.130 us; speedup vs baseline: 2.1068x; 1.0635x over previous
//
#include <hip/hip_runtime.h>
#include <hip/hip_bf16.h>

#define N_NODES   20000
#define N_EDGES   100000
#define N_REL     1000
#define F_DIM     128
#define N_HEAD    4
#define HC        512      // N_HEAD * F_DIM
#define HC2       256      // HC/2 (bf16 pairs)
#define N_LAYERS  4
#define REL_EXT_ROWS 1008  // 1000 relations + 1 mean row
#define NEG_SLOPE 0.2f
#define NODE_MB   ((N_NODES + 63) / 64)      // 313
#define REL_MB    ((REL_EXT_ROWS + 63) / 64) // 16

typedef __attribute__((ext_vector_type(8))) short short8;
typedef __attribute__((ext_vector_type(4))) float floatx4;

__device__ __forceinline__ float loadIn(const void* p, size_t i, int f32) {
    if (f32) return ((const float*)p)[i];
    union { unsigned int u; float f; } c;
    c.u = ((unsigned int)((const unsigned short*)p)[i]) << 16;
    return c.f;
}

__device__ __forceinline__ unsigned short f2bf(float v) {
    __hip_bfloat16 b = __float2bfloat16(v);
    return *(unsigned short*)&b;
}

__device__ __forceinline__ void unpack2(unsigned int u, float& lo, float& hi) {
    union { unsigned int u; float f; } a, b;
    a.u = u << 16;
    b.u = u & 0xFFFF0000u;
    lo = a.f; hi = b.f;
}

// ---------------- dtype detection ----------------
__global__ void detect_kernel(const unsigned short* __restrict__ x, int* __restrict__ flag) {
    int t = threadIdx.x;  // 64
    int cnt = 0;
    for (int j = t; j < 256; j += 64) {
        int e = (x[j] >> 7) & 0xFF;
        if (e >= 143) cnt++;
    }
    for (int off = 32; off; off >>= 1) cnt += __shfl_xor(cnt, off);
    if (t == 0) flag[0] = (cnt >= 8) ? 1 : 0;
}

// ---------------- preprocessing ----------------

__global__ void hist_kernel(const int* __restrict__ dst, const int* __restrict__ rel,
                            int* __restrict__ deg, int* __restrict__ rcount) {
    int e = blockIdx.x * 256 + threadIdx.x;
    if (e < N_EDGES) {
        atomicAdd(&deg[dst[e]], 1);
        atomicAdd(&rcount[rel[e]], 1);
    }
}

__global__ void ea_mean_kernel(const int* __restrict__ rcount,
                               const void* __restrict__ relations,
                               float* __restrict__ ea_mean, const int* __restrict__ flag) {
    int f32 = flag[0];
    int b = blockIdx.x;
    int t = threadIdx.x;
    int col = t & 127;
    int rhalf = t >> 7;
    float acc = 0.f;
    for (int j = 0; j < 4; ++j) {
        int r = b * 8 + j * 2 + rhalf;
        acc += (float)rcount[r] * loadIn(relations, (size_t)r * F_DIM + col, f32);
    }
    __shared__ float part[256];
    part[t] = acc;
    __syncthreads();
    if (t < 128)
        atomicAdd(&ea_mean[col], (part[t] + part[t + 128]) * (1.f / (float)N_EDGES));
}

__global__ void relext_kernel(const void* __restrict__ relations,
                              const float* __restrict__ ea_mean,
                              unsigned short* __restrict__ rel_ext, const int* __restrict__ flag) {
    int idx = blockIdx.x * 256 + threadIdx.x;
    if (idx >= REL_EXT_ROWS * F_DIM) return;
    int f32 = flag[0];
    int r = idx >> 7;
    int c = idx & 127;
    float v;
    if (r < N_REL)       v = loadIn(relations, idx, f32);
    else if (r == N_REL) v = ea_mean[c];
    else                 v = 0.f;
    rel_ext[idx] = f2bf(v);
}

__global__ void scan_kernel(const int* __restrict__ deg,
                            int* __restrict__ row_start, int* __restrict__ cursor) {
    __shared__ int part[1024];
    int t = threadIdx.x;
    const int CH = (N_NODES + 1023) / 1024;  // 20
    int base = t * CH;
    int sum = 0;
    for (int j = 0; j < CH; ++j) {
        int idx = base + j;
        if (idx < N_NODES) sum += deg[idx];
    }
    part[t] = sum;
    __syncthreads();
    for (int off = 1; off < 1024; off <<= 1) {
        int u = (t >= off) ? part[t - off] : 0;
        __syncthreads();
        part[t] += u;
        __syncthreads();
    }
    int run = part[t] - sum;
    for (int j = 0; j < CH; ++j) {
        int idx = base + j;
        if (idx < N_NODES) {
            row_start[idx] = run;
            cursor[idx] = run;
            run += deg[idx];
        }
    }
    if (t == 1023) row_start[N_NODES] = part[1023];
}

__global__ void scatter_kernel(const int* __restrict__ src, const int* __restrict__ dst,
                               const int* __restrict__ rel, int* __restrict__ cursor,
                               int* __restrict__ csr_pack) {
    int e = blockIdx.x * 256 + threadIdx.x;
    if (e < N_EDGES) {
        int d = dst[e];
        int p = atomicAdd(&cursor[d], 1);
        csr_pack[p] = src[e] | (rel[e] << 16);
    }
}

__global__ void tail_kernel(const void* __restrict__ relations, void* __restrict__ out,
                            const int* __restrict__ flag) {
    int i = blockIdx.x * 256 + threadIdx.x;
    if (i >= N_REL * F_DIM) return;
    int f32 = flag[0];
    float v = loadIn(relations, i, f32);
    size_t o = (size_t)N_NODES * F_DIM + i;
    if (f32) ((float*)out)[o] = v;
    else     ((unsigned short*)out)[o] = f2bf(v);
}

// ---------------- weight transpose: W[l][128 k][512 n] -> Wt[mat][512 n][128 k] bf16 ----------------
__global__ void w_transpose_kernel(const void* __restrict__ Wl, const void* __restrict__ Wr,
                                   const void* __restrict__ We,
                                   unsigned short* __restrict__ Wt, const int* __restrict__ flag) {
    int f32 = flag[0];
    int k0 = blockIdx.x * 64;
    int n0 = blockIdx.y * 64;
    int mat = blockIdx.z;
    const void* src = (mat < 4) ? Wl : (mat < 8 ? Wr : We);
    size_t base = (size_t)(mat & 3) * F_DIM * HC;
    unsigned short* dst = Wt + (size_t)mat * HC * F_DIM;
    __shared__ float T[64][65];
    int t = threadIdx.x;
    int r = t >> 2, cq = t & 3;
    for (int j = 0; j < 16; ++j) {
        int n = cq * 16 + j;
        T[n][r] = loadIn(src, base + (size_t)(k0 + r) * HC + n0 + n, f32);
    }
    __syncthreads();
    for (int j = 0; j < 16; ++j) {
        int k = cq * 16 + j;
        dst[(size_t)(n0 + r) * F_DIM + k0 + k] = f2bf(T[r][k]);
    }
}

// ---------------- merged projection GEMM (node + rel in one launch) ----------------
__launch_bounds__(256, 4)
__global__ void proj_kernel(const void* __restrict__ A_node, int a_input,
                            const unsigned short* __restrict__ rel_ext,
                            const unsigned short* __restrict__ Wlt,
                            const unsigned short* __restrict__ Wrt,
                            const unsigned short* __restrict__ Wet,
                            const void* __restrict__ bl, const void* __restrict__ br,
                            size_t boff,
                            unsigned short* __restrict__ xl,
                            unsigned short* __restrict__ xr,
                            unsigned short* __restrict__ re,
                            const int* __restrict__ flag) {
    __shared__ __align__(16) short As[64][136];    // 17.4 KB
    __shared__ __align__(16) short BtRaw[128 * 72];// 18.4 KB; Cs view: stride 136
    int f32 = flag[0];
    int isNode = (blockIdx.x < NODE_MB);
    int m0 = (isNode ? blockIdx.x : (blockIdx.x - NODE_MB)) * 64;
    int M = isNode ? N_NODES : REL_EXT_ROWS;
    int tpb = isNode ? 2 : 1;
    int a_f32 = (isNode && a_input) ? f32 : 0;
    const void* A = isNode ? A_node : (const void*)rel_ext;
    int t = threadIdx.x;

    for (int j = 0; j < 4; ++j) {
        int c = t + j * 256;
        int row = c >> 4;
        int colc = (c & 15) * 8;
        int gm = m0 + row;
        short8 v = (short8){0, 0, 0, 0, 0, 0, 0, 0};
        if (gm < M) {
            size_t idx = (size_t)gm * F_DIM + colc;
            if (a_f32) {
                const float* Af = (const float*)A;
                for (int q = 0; q < 8; ++q) v[q] = (short)f2bf(Af[idx + q]);
            } else {
                v = *(const short8*)((const unsigned short*)A + idx);
            }
        }
        *(short8*)&As[row][colc] = v;
    }

    int wave = t >> 6, lane = t & 63;
    int wm = (wave >> 1) * 32, wn = (wave & 1) * 64;
    int r16 = lane & 15, quad = lane >> 4;

    for (int it = 0; it < tpb; ++it) {
        int nt = isNode ? (blockIdx.y * 2 + it) : blockIdx.y;
        const unsigned short* Wt = isNode ? ((nt < 4) ? Wlt : Wrt) : Wet;
        int n0 = (nt & 3) * 128;

        floatx4 acc[2][4];
        for (int mi = 0; mi < 2; ++mi)
            for (int ni = 0; ni < 4; ++ni)
                acc[mi][ni] = (floatx4){0.f, 0.f, 0.f, 0.f};

        for (int half = 0; half < 2; ++half) {
            __syncthreads();
            for (int j = 0; j < 4; ++j) {
                int c = t + j * 256;
                int nl = c >> 3;
                int kc = (c & 7) * 8;
                *(short8*)&BtRaw[nl * 72 + kc] =
                    *(const short8*)(Wt + (size_t)(n0 + nl) * F_DIM + half * 64 + kc);
            }
            __syncthreads();

            for (int kk = 0; kk < 2; ++kk) {
                short8 a[2], b[4];
                for (int mi = 0; mi < 2; ++mi)
                    a[mi] = *(const short8*)&As[wm + mi * 16 + r16][half * 64 + kk * 32 + quad * 8];
                for (int ni = 0; ni < 4; ++ni)
                    b[ni] = *(const short8*)&BtRaw[(wn + ni * 16 + r16) * 72 + kk * 32 + quad * 8];
                for (int mi = 0; mi < 2; ++mi)
                    for (int ni = 0; ni < 4; ++ni)
                        acc[mi][ni] = __builtin_amdgcn_mfma_f32_16x16x32_bf16(a[mi], b[ni], acc[mi][ni], 0, 0, 0);
            }
        }

        const void* bias = isNode ? ((nt < 4) ? bl : br) : nullptr;
        unsigned short* out = isNode ? ((nt < 4) ? xl : xr) : re;
        __syncthreads();
        for (int mi = 0; mi < 2; ++mi) {
            for (int ni = 0; ni < 4; ++ni) {
                int col = wn + ni * 16 + r16;
                float bv = bias ? loadIn(bias, boff + n0 + col, f32) : 0.f;
                for (int r = 0; r < 4; ++r) {
                    int rowl = wm + mi * 16 + quad * 4 + r;
                    BtRaw[rowl * 136 + col] = (short)f2bf(acc[mi][ni][r] + bv);
                }
            }
        }
        __syncthreads();
        for (int j = 0; j < 4; ++j) {
            int c = t + j * 256;
            int rowl = c >> 4;
            int colc = (c & 15) * 8;
            int gm = m0 + rowl;
            if (gm < M)
                *(short8*)(out + (size_t)gm * HC + n0 + colc) =
                    *(const short8*)&BtRaw[rowl * 136 + colc];
        }
    }
}

// ---------------- edge kernel: r7 structure + no-max exp + batch-4 MLP pipeline ----------------
// One block per dst node; wave h = head h; ALL waves walk ALL edges; lane owns channels
// (2*lane, 2*lane+1). Edges processed in batches of 4 with a 1-batch-deep software pipeline:
// 8 independent loads (next batch) in flight while computing the current 4 edges
// (their 64-lane reduces are mutually independent -> ILP). Outstanding loads/wave: 2 -> 8.
__launch_bounds__(256)
__global__ void edge_kernel(const unsigned int* __restrict__ xl2,
                            const unsigned int* __restrict__ xr2,
                            const unsigned int* __restrict__ re2,
                            const int* __restrict__ row_start,
                            const int* __restrict__ csr_pack,
                            const void* __restrict__ att, size_t att_off,
                            const void* __restrict__ bias, size_t bias_off,
                            void* __restrict__ hout, int final_layer,
                            const int* __restrict__ flag) {
    int f32 = flag[0];
    int i = blockIdx.x;
    int h = threadIdx.x >> 6;
    int lane = threadIdx.x & 63;
    int pidx = h * 64 + lane;

    float xr0, xr1; unpack2(xr2[(size_t)i * HC2 + pidx], xr0, xr1);
    float a0 = loadIn(att, att_off + h * F_DIM + 2 * lane, f32);
    float a1 = loadIn(att, att_off + h * F_DIM + 2 * lane + 1, f32);
    float er0, er1; unpack2(re2[(size_t)N_REL * HC2 + pidx], er0, er1);

    // self-loop seed
    float xs0, xs1; unpack2(xl2[(size_t)i * HC2 + pidx], xs0, xs1);
    float t0 = xs0 + xr0 + er0;
    float t1 = xs1 + xr1 + er1;
    t0 = fmaxf(t0, NEG_SLOPE * t0);
    t1 = fmaxf(t1, NEG_SLOPE * t1);
    float part = t0 * a0 + t1 * a1;
    for (int off = 32; off; off >>= 1) part += __shfl_xor(part, off);
    part = fminf(fmaxf(part, -60.f), 60.f);
    float p = __expf(part);
    float s = p, acc0 = p * xs0, acc1 = p * xs1;

    int e0 = row_start[i], e1 = row_start[i + 1];
    if (e0 < 0) e0 = 0;
    if (e1 > N_EDGES) e1 = N_EDGES;
    if (e1 < e0) e1 = e0;

    unsigned int xv[4], rv[4];
    #pragma unroll
    for (int k = 0; k < 4; ++k) { xv[k] = 0; rv[k] = 0; }
    int b = e0;
    int nb = e1 - b; if (nb > 4) nb = 4;
    #pragma unroll
    for (int k = 0; k < 4; ++k) {
        if (k < nb) {
            int pk = csr_pack[b + k];
            int sn = pk & 0xFFFF;        if (sn >= N_NODES) sn = 0;
            int rn = (pk >> 16) & 0x3FF; if (rn > N_REL) rn = N_REL;
            xv[k] = xl2[(size_t)sn * HC2 + pidx];
            rv[k] = re2[(size_t)rn * HC2 + pidx];
        }
    }
    while (b < e1) {
        int bn = b + 4;
        int nbn = e1 - bn; if (nbn > 4) nbn = 4; if (nbn < 0) nbn = 0;
        unsigned int xvn[4], rvn[4];
        #pragma unroll
        for (int k = 0; k < 4; ++k) { xvn[k] = 0; rvn[k] = 0; }
        #pragma unroll
        for (int k = 0; k < 4; ++k) {       // prefetch next batch: 8 independent loads
            if (k < nbn) {
                int pk = csr_pack[bn + k];
                int sn = pk & 0xFFFF;        if (sn >= N_NODES) sn = 0;
                int rn = (pk >> 16) & 0x3FF; if (rn > N_REL) rn = N_REL;
                xvn[k] = xl2[(size_t)sn * HC2 + pidx];
                rvn[k] = re2[(size_t)rn * HC2 + pidx];
            }
        }
        #pragma unroll
        for (int k = 0; k < 4; ++k) {       // compute current batch (independent reduces)
            if (k < nb) {
                float xl0, xl1; unpack2(xv[k], xl0, xl1);
                float ee0, ee1; unpack2(rv[k], ee0, ee1);
                float u0 = xl0 + xr0 + ee0;
                float u1 = xl1 + xr1 + ee1;
                u0 = fmaxf(u0, NEG_SLOPE * u0);
                u1 = fmaxf(u1, NEG_SLOPE * u1);
                float pe = u0 * a0 + u1 * a1;
                for (int off = 32; off; off >>= 1) pe += __shfl_xor(pe, off);
                pe = fminf(fmaxf(pe, -60.f), 60.f);
                float pp = __expf(pe);
                s += pp;
                acc0 += pp * xl0;
                acc1 += pp * xl1;
            }
        }
        #pragma unroll
        for (int k = 0; k < 4; ++k) { xv[k] = xvn[k]; rv[k] = rvn[k]; }
        b = bn; nb = nbn;
    }

    float inv = 1.f / s;
    __shared__ float lsum[N_HEAD][F_DIM];
    lsum[h][2 * lane]     = acc0 * inv;
    lsum[h][2 * lane + 1] = acc1 * inv;
    __syncthreads();
    if (threadIdx.x < F_DIM) {
        int c = threadIdx.x;
        float v = (lsum[0][c] + lsum[1][c] + lsum[2][c] + lsum[3][c]) * 0.25f
                + loadIn(bias, bias_off + c, f32);
        size_t o = (size_t)i * F_DIM + c;
        if (final_layer && f32) ((float*)hout)[o] = v;
        else                    ((unsigned short*)hout)[o] = f2bf(v);
    }
}

// ---------------- launch ----------------

extern "C" void kernel_launch(void* const* d_in, const int* in_sizes, int n_in,
                              void* d_out, int out_size, void* d_ws, size_t ws_size,
                              hipStream_t stream) {
    const void* x          = d_in[0];
    const int*  edge_index = (const int*)d_in[1];
    const void* relations  = d_in[2];
    const int*  rel_index  = (const int*)d_in[3];
    const void* Wl         = d_in[4];
    const void* bl         = d_in[5];
    const void* Wr         = d_in[6];
    const void* br         = d_in[7];
    const void* We         = d_in[8];
    const void* att        = d_in[9];
    const void* bias       = d_in[10];

    char* ws = (char*)d_ws;
    size_t off = 0;
    auto alloc = [&](size_t bytes) -> void* {
        void* p = ws + off;
        off = (off + bytes + 255) & ~(size_t)255;
        return p;
    };
    int*            flag     = (int*)alloc(4);
    int*            deg      = (int*)alloc(N_NODES * 4);
    int*            row_start= (int*)alloc((N_NODES + 1) * 4);
    int*            cursor   = (int*)alloc(N_NODES * 4);
    int*            rcount   = (int*)alloc(N_REL * 4);
    float*          ea_mean  = (float*)alloc(F_DIM * 4);
    int*            csr_pack = (int*)alloc(N_EDGES * 4);
    unsigned short* rel_ext  = (unsigned short*)alloc((size_t)REL_EXT_ROWS * F_DIM * 2);
    unsigned short* Wt       = (unsigned short*)alloc((size_t)12 * HC * F_DIM * 2);  // 1.57 MB
    unsigned short* re       = (unsigned short*)alloc((size_t)REL_EXT_ROWS * HC * 2);
    unsigned short* hbuf     = (unsigned short*)alloc((size_t)N_NODES * F_DIM * 2);
    unsigned short* xl       = (unsigned short*)alloc((size_t)N_NODES * HC * 2);
    unsigned short* xr       = (unsigned short*)alloc((size_t)N_NODES * HC * 2);
    // total ~49 MB

    const int* esrc = edge_index;
    const int* edst = edge_index + N_EDGES;

    detect_kernel<<<1, 64, 0, stream>>>((const unsigned short*)x, flag);
    hipMemsetAsync(rcount, 0, N_REL * 4, stream);
    hipMemsetAsync(deg, 0, N_NODES * 4, stream);
    hipMemsetAsync(ea_mean, 0, F_DIM * 4, stream);
    hist_kernel<<<(N_EDGES + 255) / 256, 256, 0, stream>>>(edst, rel_index, deg, rcount);
    ea_mean_kernel<<<N_REL / 8, 256, 0, stream>>>(rcount, relations, ea_mean, flag);
    relext_kernel<<<(REL_EXT_ROWS * F_DIM + 255) / 256, 256, 0, stream>>>(relations, ea_mean, rel_ext, flag);
    scan_kernel<<<1, 1024, 0, stream>>>(deg, row_start, cursor);
    scatter_kernel<<<(N_EDGES + 255) / 256, 256, 0, stream>>>(esrc, edst, rel_index, cursor, csr_pack);
    w_transpose_kernel<<<dim3(2, 8, 12), 256, 0, stream>>>(Wl, Wr, We, Wt, flag);
    tail_kernel<<<(N_REL * F_DIM + 255) / 256, 256, 0, stream>>>(relations, d_out, flag);

    const void* hin = x;
    int a_input = 1;
    for (int l = 0; l < N_LAYERS; ++l) {
        const unsigned short* Wlt = Wt + (size_t)l * HC * F_DIM;
        const unsigned short* Wrt = Wt + (size_t)(4 + l) * HC * F_DIM;
        const unsigned short* Wet = Wt + (size_t)(8 + l) * HC * F_DIM;
        // merged node+rel projection: 329 x 4 blocks
        proj_kernel<<<dim3(NODE_MB + REL_MB, 4), 256, 0, stream>>>(
            hin, a_input, rel_ext, Wlt, Wrt, Wet,
            bl, br, (size_t)l * HC,
            xl, xr, re, flag);
        int final_layer = (l == N_LAYERS - 1);
        void* hout = final_layer ? d_out : (void*)hbuf;
        edge_kernel<<<N_NODES, 256, 0, stream>>>(
            (const unsigned int*)xl, (const unsigned int*)xr, (const unsigned int*)re,
            row_start, csr_pack,
            att, (size_t)l * N_HEAD * F_DIM,
            bias, (size_t)l * F_DIM,
            hout, final_layer, flag);
        hin = hbuf;
        a_input = 0;
    }
}